// Round 1
// baseline (5407.478 us; speedup 1.0000x reference)
//
#include <hip/hip_runtime.h>

#define BN 16
#define NN 200000
#define TOPK 6000
#define POSTK 1000
#define KEY_INV 0x407FFFFFu      /* key_of(-1.0f) */
#define KEY_NEGHALF 0x40FFFFFFu  /* key_of(-0.5f); valid <=> key > this */

// Decision-critical math must match CPU reference bit-for-bit: no FMA contraction.
#pragma clang fp contract(off)

__device__ __forceinline__ float exp_cr(float x) {
  // correctly-rounded f32 exp via double (matches glibc expf used by XLA CPU)
  return (float)exp((double)x);
}

__device__ __forceinline__ unsigned key_of(float s) {
  unsigned u = __float_as_uint(s);
  return (u & 0x80000000u) ? ~u : (u | 0x80000000u);
}

__device__ __forceinline__ void decode_box(float4 a, float4 d, float W1, float H1,
                                           float& x1, float& y1, float& x2, float& y2,
                                           bool& valid) {
  float aw = a.z - a.x;
  float ah = a.w - a.y;
  float ax = a.x + 0.5f * aw;
  float ay = a.y + 0.5f * ah;
  float px = ax + d.x * aw;
  float py = ay + d.y * ah;
  float cz = fminf(fmaxf(d.z, -10.0f), 10.0f);
  float cw = fminf(fmaxf(d.w, -10.0f), 10.0f);
  float pw = aw * exp_cr(cz);
  float ph = ah * exp_cr(cw);
  x1 = fminf(fmaxf(px - 0.5f * pw, 0.0f), W1);
  y1 = fminf(fmaxf(py - 0.5f * ph, 0.0f), H1);
  x2 = fminf(fmaxf(px + 0.5f * pw, 0.0f), W1);
  y2 = fminf(fmaxf(py + 0.5f * ph, 0.0f), H1);
  valid = ((x2 - x1) >= 16.0f) && ((y2 - y1) >= 16.0f);
}

__device__ __forceinline__ float score_of(float lg, bool valid) {
  float e = exp_cr(-lg);          // f32 pipeline, exp correctly rounded
  float s = 1.0f / (1.0f + e);    // IEEE-exact f32 add + div
  return valid ? s : -1.0f;
}

// ---------------- K1: score + key + 16-bit histogram ----------------
__global__ void k_score(const float4* __restrict__ anchors, const int* __restrict__ isz,
                        const float* __restrict__ logits, const float4* __restrict__ deltas,
                        unsigned* __restrict__ keys, unsigned* __restrict__ hist1,
                        unsigned* __restrict__ histInv) {
  int i = blockIdx.x * blockDim.x + threadIdx.x;
  if (i >= BN * NN) return;
  int b = i / NN;
  float4 a = anchors[i];
  float4 d = deltas[i];
  float H1 = (float)isz[2 * b] - 1.0f;
  float W1 = (float)isz[2 * b + 1] - 1.0f;
  float x1, y1, x2, y2; bool valid;
  decode_box(a, d, W1, H1, x1, y1, x2, y2, valid);
  float sc = score_of(logits[i], valid);
  unsigned key = key_of(sc);
  keys[i] = key;
  if (valid) {
    atomicAdd(&hist1[(size_t)b * 65536u + (key >> 16)], 1u);
  } else {
    // all invalid keys == KEY_INV; wave-aggregate to avoid same-address contention
    unsigned long long m = __ballot(1);
    int lane = threadIdx.x & 63;
    if (lane == __ffsll((unsigned long long)m) - 1)
      atomicAdd(&histInv[b], (unsigned)__popcll(m));
  }
}

// ---------------- K2: find top-16-bit threshold bin ----------------
__global__ void k_select1(const unsigned* __restrict__ hist1,
                          const unsigned* __restrict__ histInv,
                          unsigned* __restrict__ meta) {
  int b = blockIdx.x, t = threadIdx.x;  // 256 threads
  __shared__ unsigned part[256];
  __shared__ unsigned above[256];
  const unsigned* h = hist1 + (size_t)b * 65536;
  unsigned inv = histInv[b];
  int base = t * 256;
  unsigned sum = 0;
  for (int j = 0; j < 256; ++j) {
    unsigned bin = base + j;
    unsigned c = h[bin];
    if (bin == (KEY_INV >> 16)) c += inv;
    sum += c;
  }
  part[t] = sum;
  __syncthreads();
  if (t == 0) {
    unsigned run = 0;
    for (int u = 255; u >= 0; --u) { above[u] = run; run += part[u]; }
  }
  __syncthreads();
  unsigned ab = above[t];
  if (ab < TOPK && ab + part[t] >= TOPK) {
    unsigned cum = ab;
    for (int j = 255; j >= 0; --j) {
      unsigned bin = base + j;
      unsigned c = h[bin];
      if (bin == (KEY_INV >> 16)) c += inv;
      if (cum + c >= TOPK) { meta[b * 8 + 0] = bin; meta[b * 8 + 1] = cum; break; }
      cum += c;
    }
  }
}

// ---------------- K3: low-16-bit histogram within threshold bin ----------------
__global__ void k_hist2(const unsigned* __restrict__ keys, const unsigned* __restrict__ meta,
                        unsigned* __restrict__ hist2) {
  int i = blockIdx.x * blockDim.x + threadIdx.x;
  if (i >= BN * NN) return;
  int b = i / NN;
  unsigned key = keys[i];
  unsigned T = meta[b * 8 + 0];
  if ((key >> 16) == T && key != KEY_INV)
    atomicAdd(&hist2[(size_t)b * 65536 + (key & 0xFFFFu)], 1u);
}

// ---------------- K4: exact threshold key ----------------
__global__ void k_select2(const unsigned* __restrict__ hist2,
                          const unsigned* __restrict__ histInv,
                          unsigned* __restrict__ meta) {
  int b = blockIdx.x, t = threadIdx.x;
  __shared__ unsigned part[256];
  __shared__ unsigned above[256];
  const unsigned* h = hist2 + (size_t)b * 65536;
  unsigned T = meta[b * 8 + 0], cA = meta[b * 8 + 1];
  unsigned inv = (T == (KEY_INV >> 16)) ? histInv[b] : 0u;
  unsigned R = TOPK - cA;
  int base = t * 256;
  unsigned sum = 0;
  for (int j = 0; j < 256; ++j) {
    unsigned bin = base + j;
    unsigned c = h[bin];
    if (bin == 0xFFFFu) c += inv;
    sum += c;
  }
  part[t] = sum;
  __syncthreads();
  if (t == 0) {
    unsigned run = 0;
    for (int u = 255; u >= 0; --u) { above[u] = run; run += part[u]; }
  }
  __syncthreads();
  unsigned ab = above[t];
  if (ab < R && ab + part[t] >= R) {
    unsigned cum = ab;
    for (int j = 255; j >= 0; --j) {
      unsigned bin = base + j;
      unsigned c = h[bin];
      if (bin == 0xFFFFu) c += inv;
      if (cum + c >= R) {
        unsigned K = (T << 16) | (unsigned)bin;
        unsigned nG = cA + cum;
        meta[b * 8 + 2] = K;
        meta[b * 8 + 3] = nG;
        meta[b * 8 + 4] = TOPK - nG;
        break;
      }
      cum += c;
    }
  }
}

// ---------------- K5: compact strictly-greater candidates ----------------
__global__ void k_compact(const unsigned* __restrict__ keys, const unsigned* __restrict__ meta,
                          unsigned* __restrict__ cntGt, unsigned* __restrict__ sel) {
  int i = blockIdx.x * blockDim.x + threadIdx.x;
  if (i >= BN * NN) return;
  int b = i / NN;
  unsigned K = meta[b * 8 + 2];
  if (keys[i] > K) {
    unsigned p = atomicAdd(&cntGt[b], 1u);
    sel[(size_t)b * TOPK + p] = (unsigned)(i - b * NN);
  }
}

// ---------------- K6: boundary ties -> smallest original indices ----------------
__global__ void k_resolve(const unsigned* __restrict__ keys, const unsigned* __restrict__ meta,
                          unsigned* __restrict__ sel) {
  int b = blockIdx.x, t = threadIdx.x;  // 256 threads
  __shared__ unsigned cnt[256];
  unsigned K = meta[b * 8 + 2], nG = meta[b * 8 + 3], nE = meta[b * 8 + 4];
  const unsigned* kb = keys + (size_t)b * NN;
  const int CH = (NN + 255) / 256;  // 782
  int lo = t * CH;
  int hi = lo + CH < NN ? lo + CH : NN;
  unsigned c = 0;
  for (int n = lo; n < hi; ++n) c += (kb[n] == K);
  cnt[t] = c;
  __syncthreads();
  if (t == 0) {
    unsigned run = 0;
    for (int u = 0; u < 256; ++u) { unsigned v = cnt[u]; cnt[u] = run; run += v; }
  }
  __syncthreads();
  unsigned r = cnt[t];
  for (int n = lo; n < hi && r < nE; ++n)
    if (kb[n] == K) { sel[(size_t)b * TOPK + nG + r] = (unsigned)n; ++r; }
}

// ---------------- K7: sequential NMS, candidates register-resident ----------------
__global__ __launch_bounds__(1024) void k_nms(const float4* __restrict__ anchors,
                                              const int* __restrict__ isz,
                                              const float* __restrict__ logits,
                                              const float4* __restrict__ deltas,
                                              const unsigned* __restrict__ sel,
                                              float* __restrict__ out) {
  const int b = blockIdx.x;
  const int tid = threadIdx.x;
  const int wid = tid >> 6, lane = tid & 63;
  __shared__ unsigned long long wmax[16];
  __shared__ float bb[5];
  __shared__ unsigned long long wkey[POSTK];
  float H1 = (float)isz[2 * b] - 1.0f;
  float W1 = (float)isz[2 * b + 1] - 1.0f;
  const size_t base = (size_t)b * NN;

  unsigned long long k64[6];
  float sx1[6], sy1[6], sx2[6], sy2[6], sar[6];
  for (int s = 0; s < 6; ++s) {
    k64[s] = 0ull;
    sx1[s] = sy1[s] = sx2[s] = sy2[s] = sar[s] = 0.0f;
    int p = tid + s * 1024;
    if (p < TOPK) {
      unsigned n = sel[(size_t)b * TOPK + p];
      float4 a = anchors[base + n];
      float4 d = deltas[base + n];
      float x1, y1, x2, y2; bool valid;
      decode_box(a, d, W1, H1, x1, y1, x2, y2, valid);
      float sc = score_of(logits[base + n], valid);
      unsigned key = key_of(sc);
      // 64-bit key: score-major, then smaller original index wins (argmax tie-break)
      k64[s] = ((unsigned long long)key << 32) | (unsigned)(NN - 1 - (int)n);
      sx1[s] = x1; sy1[s] = y1; sx2[s] = x2; sy2[s] = y2;
      sar[s] = (x2 - x1) * (y2 - y1);
    }
  }

  int t = 0;
  for (; t < POSTK; ++t) {
    unsigned long long m = k64[0];
    for (int s = 1; s < 6; ++s) if (k64[s] > m) m = k64[s];
    for (int off = 32; off; off >>= 1) {
      unsigned long long o = __shfl_xor(m, off, 64);
      if (o > m) m = o;
    }
    if (lane == 0) wmax[wid] = m;
    __syncthreads();
    unsigned long long fk = wmax[0];
    for (int w = 1; w < 16; ++w) { unsigned long long o = wmax[w]; if (o > fk) fk = o; }
    if ((unsigned)(fk >> 32) <= KEY_NEGHALF) break;  // all remaining picks invalid
    if (tid == 0) wkey[t] = fk;
    for (int s = 0; s < 6; ++s)
      if (k64[s] == fk) {
        bb[0] = sx1[s]; bb[1] = sy1[s]; bb[2] = sx2[s]; bb[3] = sy2[s]; bb[4] = sar[s];
      }
    __syncthreads();
    float wx1 = bb[0], wy1 = bb[1], wx2 = bb[2], wy2 = bb[3], war = bb[4];
    for (int s = 0; s < 6; ++s) {
      if (k64[s]) {
        float iw = fminf(sx2[s], wx2) - fmaxf(sx1[s], wx1);
        iw = fmaxf(iw, 0.0f);
        float ih = fminf(sy2[s], wy2) - fmaxf(sy1[s], wy1);
        ih = fmaxf(ih, 0.0f);
        float inter = iw * ih;
        float uni = (sar[s] + war) - inter;  // (areas + areas[i]) - inter, ref order
        float iou = (uni > 0.0f) ? (inter / uni) : 0.0f;  // f32 div like ref
        if (iou > 0.7f) k64[s] = 0ull;       // also kills the winner itself (iou=1)
      }
    }
  }
  for (int u = t + tid; u < POSTK; u += 1024) wkey[u] = 0ull;
  __syncthreads();

  for (int q = tid; q < POSTK; q += 1024) {
    unsigned long long wk = wkey[q];
    float px1 = 0.f, py1 = 0.f, px2 = 0.f, py2 = 0.f;
    float L = 1e-8f, d0 = 0.f, d1 = 0.f, d2 = 0.f, d3 = 0.f, V = 0.f;
    if ((unsigned)(wk >> 32) > KEY_NEGHALF) {
      unsigned n = (unsigned)(NN - 1) - (unsigned)(wk & 0xFFFFFFFFull);
      float4 a = anchors[base + n];
      float4 d = deltas[base + n];
      float x1, y1, x2, y2; bool valid;
      decode_box(a, d, W1, H1, x1, y1, x2, y2, valid);
      px1 = x1; py1 = y1; px2 = x2; py2 = y2;
      L = logits[base + n];
      d0 = d.x; d1 = d.y; d2 = d.z; d3 = d.w;
      V = 1.0f;
    }
    size_t row = (size_t)b * POSTK + q;
    float* outP = out + row * 4;
    outP[0] = px1; outP[1] = py1; outP[2] = px2; outP[3] = py2;
    out[(size_t)BN * POSTK * 4 + row] = L;
    float* outD = out + (size_t)BN * POSTK * 5 + row * 4;
    outD[0] = d0; outD[1] = d1; outD[2] = d2; outD[3] = d3;
    out[(size_t)BN * POSTK * 9 + row] = V;
  }
}

extern "C" void kernel_launch(void* const* d_in, const int* in_sizes, int n_in,
                              void* d_out, int out_size, void* d_ws, size_t ws_size,
                              hipStream_t stream) {
  const float4* anchors = (const float4*)d_in[0];
  const int* isz = (const int*)d_in[1];
  const float* logits = (const float*)d_in[2];
  const float4* deltas = (const float4*)d_in[3];
  float* out = (float*)d_out;

  unsigned* ws = (unsigned*)d_ws;
  unsigned* hist1 = ws;                                    // 16*65536 u32
  unsigned* hist2 = ws + (size_t)BN * 65536;               // 16*65536 u32
  unsigned* histInv = ws + (size_t)2 * BN * 65536;         // 16 u32
  unsigned* cntGt = histInv + 16;                          // 16 u32
  unsigned* meta = histInv + 64;                           // 16*8 u32
  unsigned* keys = meta + BN * 8;                          // 16*200000 u32
  unsigned* sel = keys + (size_t)BN * NN;                  // 16*6000 u32

  size_t zeroBytes = ((size_t)2 * BN * 65536 + 64) * sizeof(unsigned);
  hipMemsetAsync(ws, 0, zeroBytes, stream);

  int total = BN * NN;
  int nb = (total + 255) / 256;
  k_score<<<nb, 256, 0, stream>>>(anchors, isz, logits, deltas, keys, hist1, histInv);
  k_select1<<<BN, 256, 0, stream>>>(hist1, histInv, meta);
  k_hist2<<<nb, 256, 0, stream>>>(keys, meta, hist2);
  k_select2<<<BN, 256, 0, stream>>>(hist2, histInv, meta);
  k_compact<<<nb, 256, 0, stream>>>(keys, meta, cntGt, sel);
  k_resolve<<<BN, 256, 0, stream>>>(keys, meta, sel);
  k_nms<<<BN, 1024, 0, stream>>>(anchors, isz, logits, deltas, sel, out);
}

// Round 2
// 1971.703 us; speedup vs baseline: 2.7425x; 2.7425x over previous
//
#include <hip/hip_runtime.h>

#define BN 16
#define NN 200000
#define TOPK 6000
#define POSTK 1000
#define MW 285744               /* triangular matrix u64-words per image */
#define KEY_NEGHALF 0x40FFFFFFu /* key_of(-0.5f); valid <=> key > this */

// Decision-critical math must match CPU reference bit-for-bit: no FMA contraction.
#pragma clang fp contract(off)

typedef unsigned long long u64;

__device__ __forceinline__ float exp_cr(float x) {
  return (float)exp((double)x);  // correctly-rounded f32 exp via double
}

__device__ __forceinline__ unsigned key_of(float s) {
  unsigned u = __float_as_uint(s);
  return (u & 0x80000000u) ? ~u : (u | 0x80000000u);
}

__device__ __forceinline__ void decode_box(float4 a, float4 d, float W1, float H1,
                                           float& x1, float& y1, float& x2, float& y2,
                                           bool& valid) {
  float aw = a.z - a.x;
  float ah = a.w - a.y;
  float ax = a.x + 0.5f * aw;
  float ay = a.y + 0.5f * ah;
  float px = ax + d.x * aw;
  float py = ay + d.y * ah;
  float cz = fminf(fmaxf(d.z, -10.0f), 10.0f);
  float cw = fminf(fmaxf(d.w, -10.0f), 10.0f);
  float pw = aw * exp_cr(cz);
  float ph = ah * exp_cr(cw);
  x1 = fminf(fmaxf(px - 0.5f * pw, 0.0f), W1);
  y1 = fminf(fmaxf(py - 0.5f * ph, 0.0f), H1);
  x2 = fminf(fmaxf(px + 0.5f * pw, 0.0f), W1);
  y2 = fminf(fmaxf(py + 0.5f * ph, 0.0f), H1);
  valid = ((x2 - x1) >= 16.0f) && ((y2 - y1) >= 16.0f);
}

__device__ __forceinline__ float score_of(float lg, bool valid) {
  float e = exp_cr(-lg);
  float s = 1.0f / (1.0f + e);
  return valid ? s : -1.0f;
}

// triangular row offset: row i stores words (i>>6)..93
__device__ __forceinline__ size_t row_off(int i) {
  int q = i >> 6, r = i & 63;
  return (size_t)(94 * i - (32 * q * (q - 1) + q * r));
}

// ---------------- K1: keys + LDS-privatized 256-bin histogram ----------------
__global__ __launch_bounds__(256) void k_score(const float4* __restrict__ anchors,
                                               const int* __restrict__ isz,
                                               const float* __restrict__ logits,
                                               const float4* __restrict__ deltas,
                                               unsigned* __restrict__ keys,
                                               unsigned* __restrict__ hist0) {
  __shared__ unsigned h[256];
  int b = blockIdx.y;
  int idx = blockIdx.x * 256 + threadIdx.x;
  h[threadIdx.x] = 0;
  __syncthreads();
  if (idx < NN) {
    size_t i = (size_t)b * NN + idx;
    float4 a = anchors[i];
    float4 d = deltas[i];
    float H1 = (float)isz[2 * b] - 1.0f;
    float W1 = (float)isz[2 * b + 1] - 1.0f;
    float x1, y1, x2, y2; bool valid;
    decode_box(a, d, W1, H1, x1, y1, x2, y2, valid);
    float sc = score_of(logits[i], valid);
    unsigned key = key_of(sc);
    keys[i] = key;
    atomicAdd(&h[key >> 24], 1u);
  }
  __syncthreads();
  unsigned c = h[threadIdx.x];
  if (c) atomicAdd(&hist0[b * 256 + threadIdx.x], c);
}

// ---------------- K2: top byte bin ----------------
__global__ void k_sel0(const unsigned* __restrict__ hist0, unsigned* __restrict__ meta) {
  int b = blockIdx.x, t = threadIdx.x;
  __shared__ unsigned c[256];
  c[t] = hist0[b * 256 + t];
  __syncthreads();
  if (t == 0) {
    unsigned cum = 0;
    for (int u = 255; u >= 0; --u) {
      if (cum + c[u] >= TOPK) { meta[b * 8 + 0] = (unsigned)u; meta[b * 8 + 1] = cum; break; }
      cum += c[u];
    }
  }
}

// ---------------- K3: mid-16-bit histogram within byte bin ----------------
__global__ __launch_bounds__(256) void k_h1(const unsigned* __restrict__ keys,
                                            const unsigned* __restrict__ meta,
                                            unsigned* __restrict__ hist1) {
  int b = blockIdx.y;
  int idx = blockIdx.x * 256 + threadIdx.x;
  if (idx >= NN) return;
  unsigned key = keys[(size_t)b * NN + idx];
  unsigned B0 = meta[b * 8 + 0];
  if ((key >> 24) == B0)
    atomicAdd(&hist1[(size_t)b * 65536 + ((key >> 8) & 0xFFFFu)], 1u);
}

// ---------------- K4: find mid-16-bit value ----------------
__global__ void k_sel1(const unsigned* __restrict__ hist1, unsigned* __restrict__ meta) {
  int b = blockIdx.x, t = threadIdx.x;
  __shared__ unsigned part[256];
  __shared__ unsigned above[256];
  const unsigned* h = hist1 + (size_t)b * 65536;
  unsigned cA0 = meta[b * 8 + 1];
  unsigned R1 = TOPK - cA0;
  int base = t * 256;
  unsigned sum = 0;
  for (int j = 0; j < 256; ++j) sum += h[base + j];
  part[t] = sum;
  __syncthreads();
  if (t == 0) {
    unsigned run = 0;
    for (int u = 255; u >= 0; --u) { above[u] = run; run += part[u]; }
  }
  __syncthreads();
  unsigned ab = above[t];
  if (ab < R1 && ab + part[t] >= R1) {
    unsigned cum = ab;
    for (int j = 255; j >= 0; --j) {
      unsigned c = h[base + j];
      if (cum + c >= R1) {
        meta[b * 8 + 2] = (unsigned)(base + j);
        meta[b * 8 + 3] = cA0 + cum;
        break;
      }
      cum += c;
    }
  }
}

// ---------------- K5: low-byte histogram within 24-bit prefix ----------------
__global__ __launch_bounds__(256) void k_h2(const unsigned* __restrict__ keys,
                                            const unsigned* __restrict__ meta,
                                            unsigned* __restrict__ hist2) {
  int b = blockIdx.y;
  int idx = blockIdx.x * 256 + threadIdx.x;
  if (idx >= NN) return;
  unsigned key = keys[(size_t)b * NN + idx];
  unsigned pref = (meta[b * 8 + 0] << 16) | meta[b * 8 + 2];
  if ((key >> 8) == pref)
    atomicAdd(&hist2[b * 256 + (key & 0xFFu)], 1u);
}

// ---------------- K6: exact threshold key ----------------
__global__ void k_sel2(const unsigned* __restrict__ hist2, unsigned* __restrict__ meta) {
  int b = blockIdx.x, t = threadIdx.x;
  __shared__ unsigned c[256];
  c[t] = hist2[b * 256 + t];
  __syncthreads();
  if (t == 0) {
    unsigned R2 = TOPK - meta[b * 8 + 3];
    unsigned cum = 0;
    for (int u = 255; u >= 0; --u) {
      if (cum + c[u] >= R2) {
        unsigned K = (meta[b * 8 + 0] << 24) | (meta[b * 8 + 2] << 8) | (unsigned)u;
        unsigned nG = meta[b * 8 + 3] + cum;
        meta[b * 8 + 4] = K;
        meta[b * 8 + 5] = nG;
        meta[b * 8 + 6] = TOPK - nG;
        break;
      }
      cum += c[u];
    }
  }
}

// ---------------- K7: compact strictly-greater (wave-aggregated atomics) ----------------
__global__ __launch_bounds__(256) void k_compact(const unsigned* __restrict__ keys,
                                                 const unsigned* __restrict__ meta,
                                                 unsigned* __restrict__ cntGt,
                                                 unsigned* __restrict__ sel) {
  int b = blockIdx.y;
  int idx = blockIdx.x * 256 + threadIdx.x;
  int lane = threadIdx.x & 63;
  bool pred = false;
  if (idx < NN) pred = keys[(size_t)b * NN + idx] > meta[b * 8 + 4];
  u64 mask = __ballot(pred);
  if (pred) {
    int leader = __ffsll(mask) - 1;
    unsigned base = 0;
    if (lane == leader) base = atomicAdd(&cntGt[b], (unsigned)__popcll(mask));
    base = __shfl(base, leader);
    unsigned pos = base + (unsigned)__popcll(mask & ((lane == 0) ? 0ull : ((1ull << lane) - 1ull)));
    sel[(size_t)b * TOPK + pos] = (unsigned)idx;
  }
}

// ---------------- K8: boundary ties -> smallest original indices ----------------
__global__ void k_resolve(const unsigned* __restrict__ keys, const unsigned* __restrict__ meta,
                          unsigned* __restrict__ sel) {
  int b = blockIdx.x, t = threadIdx.x;  // 256 threads
  __shared__ unsigned cnt[256];
  unsigned K = meta[b * 8 + 4], nG = meta[b * 8 + 5], nE = meta[b * 8 + 6];
  const unsigned* kb = keys + (size_t)b * NN;
  const int CH = (NN + 255) / 256;
  int lo = t * CH;
  int hi = lo + CH < NN ? lo + CH : NN;
  unsigned c = 0;
  for (int n = lo; n < hi; ++n) c += (kb[n] == K);
  cnt[t] = c;
  __syncthreads();
  if (t == 0) {
    unsigned run = 0;
    for (int u = 0; u < 256; ++u) { unsigned v = cnt[u]; cnt[u] = run; run += v; }
  }
  __syncthreads();
  unsigned r = cnt[t];
  for (int n = lo; n < hi && r < nE; ++n)
    if (kb[n] == K) { sel[(size_t)b * TOPK + nG + r] = (unsigned)n; ++r; }
}

// ---------------- K9: bitonic sort 6000 candidates by (score desc, idx asc) ----------------
__global__ __launch_bounds__(1024) void k_sort(const float4* __restrict__ anchors,
                                               const int* __restrict__ isz,
                                               const unsigned* __restrict__ keys,
                                               const float4* __restrict__ deltas,
                                               const unsigned* __restrict__ sel,
                                               unsigned* __restrict__ sIdx,
                                               unsigned* __restrict__ sKey,
                                               float4* __restrict__ sBox,
                                               float* __restrict__ sAr) {
  __shared__ u64 skey[8192];  // 64 KB
  int b = blockIdx.x, tid = threadIdx.x;
  for (int p = tid; p < 8192; p += 1024) {
    u64 kk = 0;
    if (p < TOPK) {
      unsigned n = sel[(size_t)b * TOPK + p];
      kk = ((u64)keys[(size_t)b * NN + n] << 32) | (unsigned)(NN - 1 - (int)n);
    }
    skey[p] = kk;
  }
  __syncthreads();
  for (unsigned k = 2; k <= 8192; k <<= 1) {
    for (unsigned j = k >> 1; j > 0; j >>= 1) {
      for (unsigned p = tid; p < 4096; p += 1024) {
        unsigned i = ((p & ~(j - 1)) << 1) | (p & (j - 1));
        unsigned x = i | j;
        u64 a = skey[i], c = skey[x];
        bool desc = ((i & k) == 0);
        if (desc ? (a < c) : (a > c)) { skey[i] = c; skey[x] = a; }
      }
      __syncthreads();
    }
  }
  float H1 = (float)isz[2 * b] - 1.0f;
  float W1 = (float)isz[2 * b + 1] - 1.0f;
  for (int i = tid; i < TOPK; i += 1024) {
    u64 kk = skey[i];
    unsigned n = (unsigned)(NN - 1) - (unsigned)(kk & 0xFFFFFFFFull);
    sIdx[(size_t)b * TOPK + i] = n;
    sKey[(size_t)b * TOPK + i] = (unsigned)(kk >> 32);
    float4 a = anchors[(size_t)b * NN + n];
    float4 d = deltas[(size_t)b * NN + n];
    float x1, y1, x2, y2; bool valid;
    decode_box(a, d, W1, H1, x1, y1, x2, y2, valid);
    sBox[(size_t)b * TOPK + i] = make_float4(x1, y1, x2, y2);
    sAr[(size_t)b * TOPK + i] = (x2 - x1) * (y2 - y1);
  }
}

// ---------------- K10: triangular IoU>0.7 bit matrix ----------------
__global__ __launch_bounds__(256) void k_iou(const float4* __restrict__ sBox,
                                             const float* __restrict__ sAr,
                                             u64* __restrict__ mat) {
  int b = blockIdx.y, Bk = blockIdx.x, tid = threadIdx.x;
  int wv = tid >> 6, lane = tid & 63;
  __shared__ float4 cb[1024];
  __shared__ float ca[1024];
  __shared__ float4 rb[64];
  __shared__ float ra[64];
  const float4* sb = sBox + (size_t)b * TOPK;
  const float* sa = sAr + (size_t)b * TOPK;
  if (tid < 64) {
    int i = Bk * 64 + tid;
    int ic = i < TOPK ? i : TOPK - 1;
    rb[tid] = sb[ic];
    ra[tid] = sa[ic];
  }
  int nwords = 94 - Bk;
  size_t matb = (size_t)b * MW;
  for (int ch = 0; ch * 16 < nwords; ++ch) {
    int colBase = Bk * 64 + ch * 1024;
    __syncthreads();
    for (int u = tid; u < 1024; u += 256) {
      int j = colBase + u;
      int jc = j < TOPK ? j : TOPK - 1;
      cb[u] = sb[jc];
      ca[u] = sa[jc];
    }
    __syncthreads();
    int wmax = nwords - ch * 16;
    if (wmax > 16) wmax = 16;
    for (int rr = 0; rr < 16; ++rr) {
      int i = Bk * 64 + wv * 16 + rr;
      if (i >= TOPK) break;
      float4 r4 = rb[wv * 16 + rr];
      float rar = ra[wv * 16 + rr];
      size_t off = matb + row_off(i) + (size_t)(ch * 16);
      for (int wloc = 0; wloc < wmax; ++wloc) {
        float4 c4 = cb[wloc * 64 + lane];
        float car = ca[wloc * 64 + lane];
        float iw = fminf(c4.z, r4.z) - fmaxf(c4.x, r4.x);
        iw = fmaxf(iw, 0.0f);
        float ih = fminf(c4.w, r4.w) - fmaxf(c4.y, r4.y);
        ih = fmaxf(ih, 0.0f);
        float inter = iw * ih;
        float uni = (car + rar) - inter;
        bool pred = (uni > 0.0f) && ((inter / uni) > 0.7f);
        u64 w64 = __ballot(pred);
        if (lane == 0) mat[off + wloc] = w64;
      }
    }
  }
}

// ---------------- K11: sequential bitmask scan + output ----------------
__global__ __launch_bounds__(256) void k_scan(const float4* __restrict__ anchors,
                                              const int* __restrict__ isz,
                                              const float* __restrict__ logits,
                                              const float4* __restrict__ deltas,
                                              const unsigned* __restrict__ sIdx,
                                              const unsigned* __restrict__ sKey,
                                              const u64* __restrict__ mat,
                                              float* __restrict__ out) {
  int b = blockIdx.x, tid = threadIdx.x, lane = tid & 63;
  __shared__ unsigned keepL[POSTK];
  __shared__ int nkSh;
  if (tid < 64) {
    u64 rm0 = 0, rm1 = 0;  // lane holds removal words lane and 64+lane
    int nk = 0;
    const u64* mb = mat + (size_t)b * MW;
    for (int B = 0; B < 94 && nk < POSTK; ++B) {
      int jl = B * 64 + lane;
      unsigned skl = (jl < TOPK) ? sKey[(size_t)b * TOPK + jl] : 0u;
      unsigned nl = (jl < TOPK) ? sIdx[(size_t)b * TOPK + jl] : 0u;
      u64 v64 = __ballot(skl > KEY_NEGHALF);
      if (!v64) break;  // sorted desc: rest all invalid
      u64 cur = (B < 64) ? __shfl(rm0, B) : __shfl(rm1, B - 64);
      u64 alive = v64 & ~cur;
      while (alive && nk < POSTK) {
        int c = __ffsll(alive) - 1;
        int i = B * 64 + c;
        unsigned n = __shfl(nl, c);
        if (lane == 0) keepL[nk] = n;
        ++nk;
        int s = B;  // i>>6 == B
        size_t off = row_off(i);
        int len = 94 - s;
        u64 r0v = (lane < len) ? mb[off + lane] : 0ull;
        u64 r1v = (lane < len - 64) ? mb[off + 64 + lane] : 0ull;
        u64 a0 = __shfl(r0v, (lane - s) & 63);
        u64 a1a = __shfl(r0v, (lane + 64 - s) & 63);
        u64 a1b = __shfl(r1v, (lane - s) & 63);
        rm0 |= (lane >= s) ? a0 : 0ull;
        rm1 |= (lane <= 29) ? ((lane < s) ? a1a : a1b) : 0ull;
        cur = (B < 64) ? __shfl(rm0, B) : __shfl(rm1, B - 64);
        alive = v64 & ~cur;
        alive &= (c >= 63) ? 0ull : (~0ull << (c + 1));
      }
    }
    if (lane == 0) nkSh = nk;
  }
  __syncthreads();
  int nk = nkSh;
  float H1 = (float)isz[2 * b] - 1.0f;
  float W1 = (float)isz[2 * b + 1] - 1.0f;
  const size_t base = (size_t)b * NN;
  for (int q = tid; q < POSTK; q += 256) {
    float px1 = 0.f, py1 = 0.f, px2 = 0.f, py2 = 0.f;
    float L = 1e-8f, d0 = 0.f, d1 = 0.f, d2 = 0.f, d3 = 0.f, V = 0.f;
    if (q < nk) {
      unsigned n = keepL[q];
      float4 a = anchors[base + n];
      float4 d = deltas[base + n];
      float x1, y1, x2, y2; bool valid;
      decode_box(a, d, W1, H1, x1, y1, x2, y2, valid);
      px1 = x1; py1 = y1; px2 = x2; py2 = y2;
      L = logits[base + n];
      d0 = d.x; d1 = d.y; d2 = d.z; d3 = d.w;
      V = 1.0f;
    }
    size_t row = (size_t)b * POSTK + q;
    float* outP = out + row * 4;
    outP[0] = px1; outP[1] = py1; outP[2] = px2; outP[3] = py2;
    out[(size_t)BN * POSTK * 4 + row] = L;
    float* outD = out + (size_t)BN * POSTK * 5 + row * 4;
    outD[0] = d0; outD[1] = d1; outD[2] = d2; outD[3] = d3;
    out[(size_t)BN * POSTK * 9 + row] = V;
  }
}

extern "C" void kernel_launch(void* const* d_in, const int* in_sizes, int n_in,
                              void* d_out, int out_size, void* d_ws, size_t ws_size,
                              hipStream_t stream) {
  const float4* anchors = (const float4*)d_in[0];
  const int* isz = (const int*)d_in[1];
  const float* logits = (const float*)d_in[2];
  const float4* deltas = (const float4*)d_in[3];
  float* out = (float*)d_out;

  // Workspace layout (u32 units). The bit matrix (36.6 MB) aliases the
  // histogram/keys region — all of it is dead before k_iou writes.
  unsigned* W = (unsigned*)d_ws;
  unsigned* hist1 = W;                       // 16*65536
  unsigned* keys = W + 1048576;              // 16*200000
  unsigned* hist0 = W + 4248576;             // 16*256
  unsigned* hist2 = W + 4252672;             // 16*256
  unsigned* cntGt = W + 4256768;             // 16
  unsigned* meta = W + 4256784;              // 16*8  (alias end ~17 MB < 36.6 MB)
  u64* mat = (u64*)d_ws;                     // 16*MW u64 = 36.58 MB
  unsigned* T = W + 9143808;                 // tail (non-aliased)
  unsigned* sel = T;                         // 16*6000
  unsigned* sIdx = T + 96000;                // 16*6000
  unsigned* sKey = T + 192000;               // 16*6000
  float4* sBox = (float4*)(T + 288000);      // 16*6000 float4
  float* sAr = (float*)(T + 672000);         // 16*6000  (total ws ~39.7 MB)

  hipMemsetAsync(hist1, 0, (size_t)1048576 * 4, stream);
  hipMemsetAsync(hist0, 0, (size_t)(4096 + 4096 + 16) * 4, stream);

  dim3 gN((NN + 255) / 256, BN);
  k_score<<<gN, 256, 0, stream>>>(anchors, isz, logits, deltas, keys, hist0);
  k_sel0<<<BN, 256, 0, stream>>>(hist0, meta);
  k_h1<<<gN, 256, 0, stream>>>(keys, meta, hist1);
  k_sel1<<<BN, 256, 0, stream>>>(hist1, meta);
  k_h2<<<gN, 256, 0, stream>>>(keys, meta, hist2);
  k_sel2<<<BN, 256, 0, stream>>>(hist2, meta);
  k_compact<<<gN, 256, 0, stream>>>(keys, meta, cntGt, sel);
  k_resolve<<<BN, 256, 0, stream>>>(keys, meta, sel);
  k_sort<<<BN, 1024, 0, stream>>>(anchors, isz, keys, deltas, sel, sIdx, sKey, sBox, sAr);
  k_iou<<<dim3(94, BN), 256, 0, stream>>>(sBox, sAr, mat);
  k_scan<<<BN, 256, 0, stream>>>(anchors, isz, logits, deltas, sIdx, sKey, mat, out);
}

// Round 3
// 1314.730 us; speedup vs baseline: 4.1130x; 1.4997x over previous
//
#include <hip/hip_runtime.h>

#define BN 16
#define NN 200000
#define TOPK 6000
#define POSTK 1000
#define MW 285744               /* triangular matrix u64-words per image */
#define KEY_NEGHALF 0x40FFFFFFu /* key_of(-0.5f); valid <=> key > this */

// Decision-critical math must match CPU reference bit-for-bit: no FMA contraction.
#pragma clang fp contract(off)

typedef unsigned long long u64;

__device__ __forceinline__ float exp_cr(float x) {
  return (float)exp((double)x);  // correctly-rounded f32 exp via double
}

__device__ __forceinline__ unsigned key_of(float s) {
  unsigned u = __float_as_uint(s);
  return (u & 0x80000000u) ? ~u : (u | 0x80000000u);
}

__device__ __forceinline__ void decode_box(float4 a, float4 d, float W1, float H1,
                                           float& x1, float& y1, float& x2, float& y2,
                                           bool& valid) {
  float aw = a.z - a.x;
  float ah = a.w - a.y;
  float ax = a.x + 0.5f * aw;
  float ay = a.y + 0.5f * ah;
  float px = ax + d.x * aw;
  float py = ay + d.y * ah;
  float cz = fminf(fmaxf(d.z, -10.0f), 10.0f);
  float cw = fminf(fmaxf(d.w, -10.0f), 10.0f);
  float pw = aw * exp_cr(cz);
  float ph = ah * exp_cr(cw);
  x1 = fminf(fmaxf(px - 0.5f * pw, 0.0f), W1);
  y1 = fminf(fmaxf(py - 0.5f * ph, 0.0f), H1);
  x2 = fminf(fmaxf(px + 0.5f * pw, 0.0f), W1);
  y2 = fminf(fmaxf(py + 0.5f * ph, 0.0f), H1);
  valid = ((x2 - x1) >= 16.0f) && ((y2 - y1) >= 16.0f);
}

__device__ __forceinline__ float score_of(float lg, bool valid) {
  float e = exp_cr(-lg);
  float s = 1.0f / (1.0f + e);
  return valid ? s : -1.0f;
}

// ---------------- K1: keys + wave-aggregated LDS histogram + sharded merge ----------------
__global__ __launch_bounds__(256) void k_score(const float4* __restrict__ anchors,
                                               const int* __restrict__ isz,
                                               const float* __restrict__ logits,
                                               const float4* __restrict__ deltas,
                                               unsigned* __restrict__ keys,
                                               unsigned* __restrict__ hist0) {
  __shared__ unsigned h[256];
  int b = blockIdx.y;
  int idx = blockIdx.x * 256 + threadIdx.x;
  int lane = threadIdx.x & 63;
  h[threadIdx.x] = 0;
  __syncthreads();
  unsigned bin = 0;
  bool active = idx < NN;
  if (active) {
    size_t i = (size_t)b * NN + idx;
    float4 a = anchors[i];
    float4 d = deltas[i];
    float H1 = (float)isz[2 * b] - 1.0f;
    float W1 = (float)isz[2 * b + 1] - 1.0f;
    float x1, y1, x2, y2; bool valid;
    decode_box(a, d, W1, H1, x1, y1, x2, y2, valid);
    float sc = score_of(logits[i], valid);
    unsigned key = key_of(sc);
    keys[i] = key;
    bin = key >> 24;
  }
  // match-any aggregation: one LDS atomic per distinct bin per wave (~3 typical)
  u64 act = __ballot(active);
  while (act) {
    int l = __ffsll(act) - 1;
    unsigned vb = __shfl(bin, l);
    u64 same = __ballot(bin == vb) & act;
    if (lane == l) atomicAdd(&h[vb], (unsigned)__popcll(same));
    act &= ~same;
  }
  __syncthreads();
  unsigned c = h[threadIdx.x];
  if (c) atomicAdd(&hist0[((size_t)b * 8 + (blockIdx.x & 7)) * 256 + threadIdx.x], c);
}

// ---------------- K2: top byte bin (sum 8 shards) ----------------
__global__ void k_sel0(const unsigned* __restrict__ hist0, unsigned* __restrict__ meta) {
  int b = blockIdx.x, t = threadIdx.x;
  __shared__ unsigned c[256];
  unsigned s = 0;
  for (int sh = 0; sh < 8; ++sh) s += hist0[((size_t)b * 8 + sh) * 256 + t];
  c[t] = s;
  __syncthreads();
  if (t == 0) {
    unsigned cum = 0;
    for (int u = 255; u >= 0; --u) {
      if (cum + c[u] >= TOPK) { meta[b * 8 + 0] = (unsigned)u; meta[b * 8 + 1] = cum; break; }
      cum += c[u];
    }
  }
}

// ---------------- K3: mid-16-bit histogram within byte bin ----------------
__global__ __launch_bounds__(256) void k_h1(const unsigned* __restrict__ keys,
                                            const unsigned* __restrict__ meta,
                                            unsigned* __restrict__ hist1) {
  int b = blockIdx.y;
  int idx = blockIdx.x * 256 + threadIdx.x;
  if (idx >= NN) return;
  unsigned key = keys[(size_t)b * NN + idx];
  unsigned B0 = meta[b * 8 + 0];
  if ((key >> 24) == B0)
    atomicAdd(&hist1[(size_t)b * 65536 + ((key >> 8) & 0xFFFFu)], 1u);
}

// ---------------- K4: find mid-16-bit value ----------------
__global__ void k_sel1(const unsigned* __restrict__ hist1, unsigned* __restrict__ meta) {
  int b = blockIdx.x, t = threadIdx.x;
  __shared__ unsigned part[256];
  __shared__ unsigned above[256];
  const unsigned* h = hist1 + (size_t)b * 65536;
  unsigned cA0 = meta[b * 8 + 1];
  unsigned R1 = TOPK - cA0;
  int base = t * 256;
  unsigned sum = 0;
  for (int j = 0; j < 256; ++j) sum += h[base + j];
  part[t] = sum;
  __syncthreads();
  if (t == 0) {
    unsigned run = 0;
    for (int u = 255; u >= 0; --u) { above[u] = run; run += part[u]; }
  }
  __syncthreads();
  unsigned ab = above[t];
  if (ab < R1 && ab + part[t] >= R1) {
    unsigned cum = ab;
    for (int j = 255; j >= 0; --j) {
      unsigned c = h[base + j];
      if (cum + c >= R1) {
        meta[b * 8 + 2] = (unsigned)(base + j);
        meta[b * 8 + 3] = cA0 + cum;
        break;
      }
      cum += c;
    }
  }
}

// ---------------- K5: low-byte histogram within 24-bit prefix ----------------
__global__ __launch_bounds__(256) void k_h2(const unsigned* __restrict__ keys,
                                            const unsigned* __restrict__ meta,
                                            unsigned* __restrict__ hist2) {
  int b = blockIdx.y;
  int idx = blockIdx.x * 256 + threadIdx.x;
  if (idx >= NN) return;
  unsigned key = keys[(size_t)b * NN + idx];
  unsigned pref = (meta[b * 8 + 0] << 16) | meta[b * 8 + 2];
  if ((key >> 8) == pref)
    atomicAdd(&hist2[b * 256 + (key & 0xFFu)], 1u);
}

// ---------------- K6: exact threshold key ----------------
__global__ void k_sel2(const unsigned* __restrict__ hist2, unsigned* __restrict__ meta) {
  int b = blockIdx.x, t = threadIdx.x;
  __shared__ unsigned c[256];
  c[t] = hist2[b * 256 + t];
  __syncthreads();
  if (t == 0) {
    unsigned R2 = TOPK - meta[b * 8 + 3];
    unsigned cum = 0;
    for (int u = 255; u >= 0; --u) {
      if (cum + c[u] >= R2) {
        unsigned K = (meta[b * 8 + 0] << 24) | (meta[b * 8 + 2] << 8) | (unsigned)u;
        unsigned nG = meta[b * 8 + 3] + cum;
        meta[b * 8 + 4] = K;
        meta[b * 8 + 5] = nG;
        meta[b * 8 + 6] = TOPK - nG;
        break;
      }
      cum += c[u];
    }
  }
}

// ---------------- K7: compact strictly-greater (one atomic per block) ----------------
// sel order is irrelevant (k_sort re-sorts), so block-count -> LDS scan -> one
// padded atomic per block -> positional writes. Kills the 42K same-cache-line
// device atomics that made this kernel 489us.
__global__ __launch_bounds__(256) void k_compact(const unsigned* __restrict__ keys,
                                                 const unsigned* __restrict__ meta,
                                                 unsigned* __restrict__ cntGt,
                                                 unsigned* __restrict__ sel) {
  __shared__ unsigned sc[256];
  __shared__ unsigned baseSh;
  int b = blockIdx.y, tid = threadIdx.x;
  const unsigned* kb = keys + (size_t)b * NN;
  unsigned K = meta[b * 8 + 4];
  int start = blockIdx.x * 8000;
  int end = start + 8000 < NN ? start + 8000 : NN;
  unsigned cnt = 0;
  for (int n = start + tid; n < end; n += 256) cnt += (kb[n] > K);
  sc[tid] = cnt;
  __syncthreads();
  if (tid == 0) {
    unsigned run = 0;
    for (int u = 0; u < 256; ++u) { unsigned v = sc[u]; sc[u] = run; run += v; }
    baseSh = run ? atomicAdd(&cntGt[b * 64], run) : 0u;
  }
  __syncthreads();
  unsigned pos = baseSh + sc[tid];
  for (int n = start + tid; n < end; n += 256)
    if (kb[n] > K) sel[(size_t)b * TOPK + pos++] = (unsigned)n;
}

// ---------------- K8: boundary ties -> smallest original indices ----------------
__global__ void k_resolve(const unsigned* __restrict__ keys, const unsigned* __restrict__ meta,
                          unsigned* __restrict__ sel) {
  int b = blockIdx.x, t = threadIdx.x;  // 256 threads
  __shared__ unsigned cnt[256];
  unsigned K = meta[b * 8 + 4], nG = meta[b * 8 + 5], nE = meta[b * 8 + 6];
  const unsigned* kb = keys + (size_t)b * NN;
  const int CH = (NN + 255) / 256;
  int lo = t * CH;
  int hi = lo + CH < NN ? lo + CH : NN;
  unsigned c = 0;
  for (int n = lo; n < hi; ++n) c += (kb[n] == K);
  cnt[t] = c;
  __syncthreads();
  if (t == 0) {
    unsigned run = 0;
    for (int u = 0; u < 256; ++u) { unsigned v = cnt[u]; cnt[u] = run; run += v; }
  }
  __syncthreads();
  unsigned r = cnt[t];
  for (int n = lo; n < hi && r < nE; ++n)
    if (kb[n] == K) { sel[(size_t)b * TOPK + nG + r] = (unsigned)n; ++r; }
}

// ---------------- K9: bitonic sort 6000 candidates by (score desc, idx asc) ----------------
__global__ __launch_bounds__(1024) void k_sort(const float4* __restrict__ anchors,
                                               const int* __restrict__ isz,
                                               const unsigned* __restrict__ keys,
                                               const float4* __restrict__ deltas,
                                               const unsigned* __restrict__ sel,
                                               unsigned* __restrict__ sIdx,
                                               unsigned* __restrict__ sKey,
                                               float4* __restrict__ sBox,
                                               float* __restrict__ sAr) {
  __shared__ u64 skey[8192];  // 64 KB
  int b = blockIdx.x, tid = threadIdx.x;
  for (int p = tid; p < 8192; p += 1024) {
    u64 kk = 0;
    if (p < TOPK) {
      unsigned n = sel[(size_t)b * TOPK + p];
      kk = ((u64)keys[(size_t)b * NN + n] << 32) | (unsigned)(NN - 1 - (int)n);
    }
    skey[p] = kk;
  }
  __syncthreads();
  for (unsigned k = 2; k <= 8192; k <<= 1) {
    for (unsigned j = k >> 1; j > 0; j >>= 1) {
      for (unsigned p = tid; p < 4096; p += 1024) {
        unsigned i = ((p & ~(j - 1)) << 1) | (p & (j - 1));
        unsigned x = i | j;
        u64 a = skey[i], c = skey[x];
        bool desc = ((i & k) == 0);
        if (desc ? (a < c) : (a > c)) { skey[i] = c; skey[x] = a; }
      }
      __syncthreads();
    }
  }
  float H1 = (float)isz[2 * b] - 1.0f;
  float W1 = (float)isz[2 * b + 1] - 1.0f;
  for (int i = tid; i < TOPK; i += 1024) {
    u64 kk = skey[i];
    unsigned n = (unsigned)(NN - 1) - (unsigned)(kk & 0xFFFFFFFFull);
    sIdx[(size_t)b * TOPK + i] = n;
    sKey[(size_t)b * TOPK + i] = (unsigned)(kk >> 32);
    float4 a = anchors[(size_t)b * NN + n];
    float4 d = deltas[(size_t)b * NN + n];
    float x1, y1, x2, y2; bool valid;
    decode_box(a, d, W1, H1, x1, y1, x2, y2, valid);
    sBox[(size_t)b * TOPK + i] = make_float4(x1, y1, x2, y2);
    sAr[(size_t)b * TOPK + i] = (x2 - x1) * (y2 - y1);
  }
}

// ---------------- K10: triangular IoU>0.7 bit matrix ----------------
__global__ __launch_bounds__(256) void k_iou(const float4* __restrict__ sBox,
                                             const float* __restrict__ sAr,
                                             u64* __restrict__ mat) {
  int b = blockIdx.y, Bk = blockIdx.x, tid = threadIdx.x;
  int wv = tid >> 6, lane = tid & 63;
  __shared__ float4 cb[1024];
  __shared__ float ca[1024];
  __shared__ float4 rb[64];
  __shared__ float ra[64];
  const float4* sb = sBox + (size_t)b * TOPK;
  const float* sa = sAr + (size_t)b * TOPK;
  if (tid < 64) {
    int i = Bk * 64 + tid;
    int ic = i < TOPK ? i : TOPK - 1;
    rb[tid] = sb[ic];
    ra[tid] = sa[ic];
  }
  int nwords = 94 - Bk;
  size_t matb = (size_t)b * MW;
  for (int ch = 0; ch * 16 < nwords; ++ch) {
    int colBase = Bk * 64 + ch * 1024;
    __syncthreads();
    for (int u = tid; u < 1024; u += 256) {
      int j = colBase + u;
      int jc = j < TOPK ? j : TOPK - 1;
      cb[u] = sb[jc];
      ca[u] = sa[jc];
    }
    __syncthreads();
    int wmax = nwords - ch * 16;
    if (wmax > 16) wmax = 16;
    for (int rr = 0; rr < 16; ++rr) {
      int i = Bk * 64 + wv * 16 + rr;
      if (i >= TOPK) break;
      float4 r4 = rb[wv * 16 + rr];
      float rar = ra[wv * 16 + rr];
      int q = i >> 6, rmod = i & 63;
      size_t off = matb + (size_t)(94 * i - (32 * q * (q - 1) + q * rmod)) + (size_t)(ch * 16);
      for (int wloc = 0; wloc < wmax; ++wloc) {
        float4 c4 = cb[wloc * 64 + lane];
        float car = ca[wloc * 64 + lane];
        float iw = fminf(c4.z, r4.z) - fmaxf(c4.x, r4.x);
        iw = fmaxf(iw, 0.0f);
        float ih = fminf(c4.w, r4.w) - fmaxf(c4.y, r4.y);
        ih = fmaxf(ih, 0.0f);
        float inter = iw * ih;
        float uni = (car + rar) - inter;
        bool pred = (uni > 0.0f) && ((inter / uni) > 0.7f);
        u64 w64 = __ballot(pred);
        if (lane == 0) mat[off + wloc] = w64;
      }
    }
  }
}

// ---------------- K11: batched-LDS sequential scan + output ----------------
// Per 64-candidate batch: 256 threads stage all 64 triangular rows (<=48KB)
// into LDS in parallel (reads the matrix exactly once, latency amortized),
// then wave 0 runs the serial pick/suppress loop entirely from LDS.
__global__ __launch_bounds__(256) void k_scan(const float4* __restrict__ anchors,
                                              const int* __restrict__ isz,
                                              const float* __restrict__ logits,
                                              const float4* __restrict__ deltas,
                                              const unsigned* __restrict__ sIdx,
                                              const unsigned* __restrict__ sKey,
                                              const u64* __restrict__ mat,
                                              float* __restrict__ out) {
  __shared__ u64 rowbuf[64 * 94];   // 48.1 KB
  __shared__ unsigned keepL[POSTK];
  __shared__ int nkSh;
  int b = blockIdx.x, tid = threadIdx.x, lane = tid & 63, wv = tid >> 6;
  const u64* mb = mat + (size_t)b * MW;
  u64 rm0 = 0, rm1 = 0;  // wave0: lane holds removal words lane and 64+lane
  int nk = 0;
  if (tid == 0) nkSh = 0;
  __syncthreads();
  for (int B = 0; B < 94; ++B) {
    if (nkSh >= POSTK) break;
    int len = 94 - B;
    // stage rows: 4 threads per row, words strided by 4
    {
      int r = tid >> 2, sub = tid & 3;
      int i = B * 64 + r;
      if (i < TOPK) {
        size_t off = (size_t)(94 * i - (32 * B * (B - 1) + B * r));
        u64* dst = &rowbuf[r * 94];
        for (int w = sub; w < len; w += 4) dst[w] = mb[off + w];
      }
    }
    __syncthreads();
    if (wv == 0) {
      int jl = B * 64 + lane;
      unsigned skl = (jl < TOPK) ? sKey[(size_t)b * TOPK + jl] : 0u;
      unsigned nl = (jl < TOPK) ? sIdx[(size_t)b * TOPK + jl] : 0u;
      u64 v64 = __ballot(skl > KEY_NEGHALF);
      u64 cur = (B < 64) ? __shfl(rm0, B) : __shfl(rm1, B - 64);
      u64 alive = v64 & ~cur;
      while (alive && nk < POSTK) {
        int c = __ffsll(alive) - 1;
        unsigned n = __shfl(nl, c);
        if (lane == 0) keepL[nk] = n;
        ++nk;
        // OR row c (LDS) into distributed removal mask
        u64 w0 = (lane >= B) ? rowbuf[c * 94 + (lane - B)] : 0ull;
        int w1i = 64 + lane;
        u64 w1 = (w1i <= 93 && w1i >= B) ? rowbuf[c * 94 + (w1i - B)] : 0ull;
        rm0 |= w0;
        rm1 |= w1;
        cur = (B < 64) ? __shfl(rm0, B) : __shfl(rm1, B - 64);
        alive = v64 & ~cur;
        alive &= (c >= 63) ? 0ull : (~0ull << (c + 1));
      }
      if (lane == 0) nkSh = nk;
    }
    __syncthreads();  // rowbuf consumed; nkSh visible at loop top
  }
  int nkF = nkSh;
  float H1 = (float)isz[2 * b] - 1.0f;
  float W1 = (float)isz[2 * b + 1] - 1.0f;
  const size_t base = (size_t)b * NN;
  for (int q = tid; q < POSTK; q += 256) {
    float px1 = 0.f, py1 = 0.f, px2 = 0.f, py2 = 0.f;
    float L = 1e-8f, d0 = 0.f, d1 = 0.f, d2 = 0.f, d3 = 0.f, V = 0.f;
    if (q < nkF) {
      unsigned n = keepL[q];
      float4 a = anchors[base + n];
      float4 d = deltas[base + n];
      float x1, y1, x2, y2; bool valid;
      decode_box(a, d, W1, H1, x1, y1, x2, y2, valid);
      px1 = x1; py1 = y1; px2 = x2; py2 = y2;
      L = logits[base + n];
      d0 = d.x; d1 = d.y; d2 = d.z; d3 = d.w;
      V = 1.0f;
    }
    size_t row = (size_t)b * POSTK + q;
    float* outP = out + row * 4;
    outP[0] = px1; outP[1] = py1; outP[2] = px2; outP[3] = py2;
    out[(size_t)BN * POSTK * 4 + row] = L;
    float* outD = out + (size_t)BN * POSTK * 5 + row * 4;
    outD[0] = d0; outD[1] = d1; outD[2] = d2; outD[3] = d3;
    out[(size_t)BN * POSTK * 9 + row] = V;
  }
}

extern "C" void kernel_launch(void* const* d_in, const int* in_sizes, int n_in,
                              void* d_out, int out_size, void* d_ws, size_t ws_size,
                              hipStream_t stream) {
  const float4* anchors = (const float4*)d_in[0];
  const int* isz = (const int*)d_in[1];
  const float* logits = (const float*)d_in[2];
  const float4* deltas = (const float4*)d_in[3];
  float* out = (float*)d_out;

  // Workspace layout (u32 units). The bit matrix (36.6 MB) aliases the
  // histogram/keys region — all of it is dead before k_iou writes.
  unsigned* W = (unsigned*)d_ws;
  unsigned* hist1 = W;                       // 16*65536
  unsigned* keys = W + 1048576;              // 16*200000
  unsigned* hist0 = W + 4248576;             // 16*8*256 (8 shards/image)
  unsigned* hist2 = W + 4281344;             // 16*256
  unsigned* cntGt = W + 4285440;             // 16*64 (one cache line per image)
  unsigned* meta = W + 4286464;              // 16*8
  u64* mat = (u64*)d_ws;                     // 16*MW u64 = 36.58 MB (aliases above)
  unsigned* T = W + 9143808;                 // tail (non-aliased)
  unsigned* sel = T;                         // 16*6000
  unsigned* sIdx = T + 96000;                // 16*6000
  unsigned* sKey = T + 192000;               // 16*6000
  float4* sBox = (float4*)(T + 288000);      // 16*6000 float4
  float* sAr = (float*)(T + 672000);         // 16*6000  (total ws ~39.7 MB)

  hipMemsetAsync(hist1, 0, (size_t)1048576 * 4, stream);
  hipMemsetAsync(hist0, 0, (size_t)(32768 + 4096 + 1024 + 128) * 4, stream);

  dim3 gN((NN + 255) / 256, BN);
  k_score<<<gN, 256, 0, stream>>>(anchors, isz, logits, deltas, keys, hist0);
  k_sel0<<<BN, 256, 0, stream>>>(hist0, meta);
  k_h1<<<gN, 256, 0, stream>>>(keys, meta, hist1);
  k_sel1<<<BN, 256, 0, stream>>>(hist1, meta);
  k_h2<<<gN, 256, 0, stream>>>(keys, meta, hist2);
  k_sel2<<<BN, 256, 0, stream>>>(hist2, meta);
  k_compact<<<dim3(25, BN), 256, 0, stream>>>(keys, meta, cntGt, sel);
  k_resolve<<<BN, 256, 0, stream>>>(keys, meta, sel);
  k_sort<<<BN, 1024, 0, stream>>>(anchors, isz, keys, deltas, sel, sIdx, sKey, sBox, sAr);
  k_iou<<<dim3(94, BN), 256, 0, stream>>>(sBox, sAr, mat);
  k_scan<<<BN, 256, 0, stream>>>(anchors, isz, logits, deltas, sIdx, sKey, mat, out);
}

// Round 4
// 1009.658 us; speedup vs baseline: 5.3558x; 1.3022x over previous
//
#include <hip/hip_runtime.h>

#define BN 16
#define NN 200000
#define TOPK 6000
#define POSTK 1000
#define MW 285744               /* triangular matrix u64-words per image */
#define KEY_NEGHALF 0x40FFFFFFu /* key_of(-0.5f); valid <=> key > this */

// Decision-critical math must match CPU reference bit-for-bit: no FMA contraction.
#pragma clang fp contract(off)

typedef unsigned long long u64;

__device__ __forceinline__ float exp_cr(float x) {
  return (float)exp((double)x);  // correctly-rounded f32 exp via double
}

__device__ __forceinline__ unsigned key_of(float s) {
  unsigned u = __float_as_uint(s);
  return (u & 0x80000000u) ? ~u : (u | 0x80000000u);
}

__device__ __forceinline__ void decode_box(float4 a, float4 d, float W1, float H1,
                                           float& x1, float& y1, float& x2, float& y2,
                                           bool& valid) {
  float aw = a.z - a.x;
  float ah = a.w - a.y;
  float ax = a.x + 0.5f * aw;
  float ay = a.y + 0.5f * ah;
  float px = ax + d.x * aw;
  float py = ay + d.y * ah;
  float cz = fminf(fmaxf(d.z, -10.0f), 10.0f);
  float cw = fminf(fmaxf(d.w, -10.0f), 10.0f);
  float pw = aw * exp_cr(cz);
  float ph = ah * exp_cr(cw);
  x1 = fminf(fmaxf(px - 0.5f * pw, 0.0f), W1);
  y1 = fminf(fmaxf(py - 0.5f * ph, 0.0f), H1);
  x2 = fminf(fmaxf(px + 0.5f * pw, 0.0f), W1);
  y2 = fminf(fmaxf(py + 0.5f * ph, 0.0f), H1);
  valid = ((x2 - x1) >= 16.0f) && ((y2 - y1) >= 16.0f);
}

__device__ __forceinline__ float score_of(float lg, bool valid) {
  float e = exp_cr(-lg);
  float s = 1.0f / (1.0f + e);
  return valid ? s : -1.0f;
}

// ---------------- K1: keys + wave-aggregated LDS histogram + sharded merge ----------------
__global__ __launch_bounds__(256) void k_score(const float4* __restrict__ anchors,
                                               const int* __restrict__ isz,
                                               const float* __restrict__ logits,
                                               const float4* __restrict__ deltas,
                                               unsigned* __restrict__ keys,
                                               unsigned* __restrict__ hist0) {
  __shared__ unsigned h[256];
  int b = blockIdx.y;
  int idx = blockIdx.x * 256 + threadIdx.x;
  int lane = threadIdx.x & 63;
  h[threadIdx.x] = 0;
  __syncthreads();
  unsigned bin = 0;
  bool active = idx < NN;
  if (active) {
    size_t i = (size_t)b * NN + idx;
    float4 a = anchors[i];
    float4 d = deltas[i];
    float H1 = (float)isz[2 * b] - 1.0f;
    float W1 = (float)isz[2 * b + 1] - 1.0f;
    float x1, y1, x2, y2; bool valid;
    decode_box(a, d, W1, H1, x1, y1, x2, y2, valid);
    float sc = score_of(logits[i], valid);
    unsigned key = key_of(sc);
    keys[i] = key;
    bin = key >> 24;
  }
  // match-any aggregation: one LDS atomic per distinct bin per wave (~3 typical)
  u64 act = __ballot(active);
  while (act) {
    int l = __ffsll(act) - 1;
    unsigned vb = __shfl(bin, l);
    u64 same = __ballot(bin == vb) & act;
    if (lane == l) atomicAdd(&h[vb], (unsigned)__popcll(same));
    act &= ~same;
  }
  __syncthreads();
  unsigned c = h[threadIdx.x];
  if (c) atomicAdd(&hist0[((size_t)b * 8 + (blockIdx.x & 7)) * 256 + threadIdx.x], c);
}

// ---------------- K2: top byte bin (sum 8 shards) ----------------
__global__ void k_sel0(const unsigned* __restrict__ hist0, unsigned* __restrict__ meta) {
  int b = blockIdx.x, t = threadIdx.x;
  __shared__ unsigned c[256];
  unsigned s = 0;
  for (int sh = 0; sh < 8; ++sh) s += hist0[((size_t)b * 8 + sh) * 256 + t];
  c[t] = s;
  __syncthreads();
  if (t == 0) {
    unsigned cum = 0;
    for (int u = 255; u >= 0; --u) {
      if (cum + c[u] >= TOPK) { meta[b * 8 + 0] = (unsigned)u; meta[b * 8 + 1] = cum; break; }
      cum += c[u];
    }
  }
}

// ---------------- K3: mid-16-bit histogram within byte bin ----------------
__global__ __launch_bounds__(256) void k_h1(const unsigned* __restrict__ keys,
                                            const unsigned* __restrict__ meta,
                                            unsigned* __restrict__ hist1) {
  int b = blockIdx.y;
  int idx = blockIdx.x * 256 + threadIdx.x;
  if (idx >= NN) return;
  unsigned key = keys[(size_t)b * NN + idx];
  unsigned B0 = meta[b * 8 + 0];
  if ((key >> 24) == B0)
    atomicAdd(&hist1[(size_t)b * 65536 + ((key >> 8) & 0xFFFFu)], 1u);
}

// ---------------- K4: find mid-16-bit value ----------------
__global__ void k_sel1(const unsigned* __restrict__ hist1, unsigned* __restrict__ meta) {
  int b = blockIdx.x, t = threadIdx.x;
  __shared__ unsigned part[256];
  __shared__ unsigned above[256];
  const unsigned* h = hist1 + (size_t)b * 65536;
  unsigned cA0 = meta[b * 8 + 1];
  unsigned R1 = TOPK - cA0;
  int base = t * 256;
  unsigned sum = 0;
  for (int j = 0; j < 256; ++j) sum += h[base + j];
  part[t] = sum;
  __syncthreads();
  if (t == 0) {
    unsigned run = 0;
    for (int u = 255; u >= 0; --u) { above[u] = run; run += part[u]; }
  }
  __syncthreads();
  unsigned ab = above[t];
  if (ab < R1 && ab + part[t] >= R1) {
    unsigned cum = ab;
    for (int j = 255; j >= 0; --j) {
      unsigned c = h[base + j];
      if (cum + c >= R1) {
        meta[b * 8 + 2] = (unsigned)(base + j);
        meta[b * 8 + 3] = cA0 + cum;
        break;
      }
      cum += c;
    }
  }
}

// ---------------- K5: low-byte histogram within 24-bit prefix ----------------
__global__ __launch_bounds__(256) void k_h2(const unsigned* __restrict__ keys,
                                            const unsigned* __restrict__ meta,
                                            unsigned* __restrict__ hist2) {
  int b = blockIdx.y;
  int idx = blockIdx.x * 256 + threadIdx.x;
  if (idx >= NN) return;
  unsigned key = keys[(size_t)b * NN + idx];
  unsigned pref = (meta[b * 8 + 0] << 16) | meta[b * 8 + 2];
  if ((key >> 8) == pref)
    atomicAdd(&hist2[b * 256 + (key & 0xFFu)], 1u);
}

// ---------------- K6: exact threshold key ----------------
__global__ void k_sel2(const unsigned* __restrict__ hist2, unsigned* __restrict__ meta) {
  int b = blockIdx.x, t = threadIdx.x;
  __shared__ unsigned c[256];
  c[t] = hist2[b * 256 + t];
  __syncthreads();
  if (t == 0) {
    unsigned R2 = TOPK - meta[b * 8 + 3];
    unsigned cum = 0;
    for (int u = 255; u >= 0; --u) {
      if (cum + c[u] >= R2) {
        unsigned K = (meta[b * 8 + 0] << 24) | (meta[b * 8 + 2] << 8) | (unsigned)u;
        unsigned nG = meta[b * 8 + 3] + cum;
        meta[b * 8 + 4] = K;
        meta[b * 8 + 5] = nG;
        meta[b * 8 + 6] = TOPK - nG;
        break;
      }
      cum += c[u];
    }
  }
}

// ---------------- K7: compact strictly-greater (one atomic per block) ----------------
__global__ __launch_bounds__(256) void k_compact(const unsigned* __restrict__ keys,
                                                 const unsigned* __restrict__ meta,
                                                 unsigned* __restrict__ cntGt,
                                                 unsigned* __restrict__ sel) {
  __shared__ unsigned sc[256];
  __shared__ unsigned baseSh;
  int b = blockIdx.y, tid = threadIdx.x;
  const unsigned* kb = keys + (size_t)b * NN;
  unsigned K = meta[b * 8 + 4];
  int start = blockIdx.x * 8000;
  int end = start + 8000 < NN ? start + 8000 : NN;
  unsigned cnt = 0;
  for (int n = start + tid; n < end; n += 256) cnt += (kb[n] > K);
  sc[tid] = cnt;
  __syncthreads();
  if (tid == 0) {
    unsigned run = 0;
    for (int u = 0; u < 256; ++u) { unsigned v = sc[u]; sc[u] = run; run += v; }
    baseSh = run ? atomicAdd(&cntGt[b * 64], run) : 0u;
  }
  __syncthreads();
  unsigned pos = baseSh + sc[tid];
  for (int n = start + tid; n < end; n += 256)
    if (kb[n] > K) sel[(size_t)b * TOPK + pos++] = (unsigned)n;
}

// ---------------- K8: boundary ties -> smallest original indices ----------------
__global__ void k_resolve(const unsigned* __restrict__ keys, const unsigned* __restrict__ meta,
                          unsigned* __restrict__ sel) {
  int b = blockIdx.x, t = threadIdx.x;  // 256 threads
  __shared__ unsigned cnt[256];
  unsigned K = meta[b * 8 + 4], nG = meta[b * 8 + 5], nE = meta[b * 8 + 6];
  const unsigned* kb = keys + (size_t)b * NN;
  const int CH = (NN + 255) / 256;
  int lo = t * CH;
  int hi = lo + CH < NN ? lo + CH : NN;
  unsigned c = 0;
  for (int n = lo; n < hi; ++n) c += (kb[n] == K);
  cnt[t] = c;
  __syncthreads();
  if (t == 0) {
    unsigned run = 0;
    for (int u = 0; u < 256; ++u) { unsigned v = cnt[u]; cnt[u] = run; run += v; }
  }
  __syncthreads();
  unsigned r = cnt[t];
  for (int n = lo; n < hi && r < nE; ++n)
    if (kb[n] == K) { sel[(size_t)b * TOPK + nG + r] = (unsigned)n; ++r; }
}

// ---------------- K9: bitonic sort 6000 candidates by (score desc, idx asc) ----------------
__global__ __launch_bounds__(1024) void k_sort(const float4* __restrict__ anchors,
                                               const int* __restrict__ isz,
                                               const unsigned* __restrict__ keys,
                                               const float4* __restrict__ deltas,
                                               const unsigned* __restrict__ sel,
                                               unsigned* __restrict__ sIdx,
                                               unsigned* __restrict__ sKey,
                                               float4* __restrict__ sBox,
                                               float* __restrict__ sAr) {
  __shared__ u64 skey[8192];  // 64 KB
  int b = blockIdx.x, tid = threadIdx.x;
  for (int p = tid; p < 8192; p += 1024) {
    u64 kk = 0;
    if (p < TOPK) {
      unsigned n = sel[(size_t)b * TOPK + p];
      kk = ((u64)keys[(size_t)b * NN + n] << 32) | (unsigned)(NN - 1 - (int)n);
    }
    skey[p] = kk;
  }
  __syncthreads();
  for (unsigned k = 2; k <= 8192; k <<= 1) {
    for (unsigned j = k >> 1; j > 0; j >>= 1) {
      for (unsigned p = tid; p < 4096; p += 1024) {
        unsigned i = ((p & ~(j - 1)) << 1) | (p & (j - 1));
        unsigned x = i | j;
        u64 a = skey[i], c = skey[x];
        bool desc = ((i & k) == 0);
        if (desc ? (a < c) : (a > c)) { skey[i] = c; skey[x] = a; }
      }
      __syncthreads();
    }
  }
  float H1 = (float)isz[2 * b] - 1.0f;
  float W1 = (float)isz[2 * b + 1] - 1.0f;
  for (int i = tid; i < TOPK; i += 1024) {
    u64 kk = skey[i];
    unsigned n = (unsigned)(NN - 1) - (unsigned)(kk & 0xFFFFFFFFull);
    sIdx[(size_t)b * TOPK + i] = n;
    sKey[(size_t)b * TOPK + i] = (unsigned)(kk >> 32);
    float4 a = anchors[(size_t)b * NN + n];
    float4 d = deltas[(size_t)b * NN + n];
    float x1, y1, x2, y2; bool valid;
    decode_box(a, d, W1, H1, x1, y1, x2, y2, valid);
    sBox[(size_t)b * TOPK + i] = make_float4(x1, y1, x2, y2);
    sAr[(size_t)b * TOPK + i] = (x2 - x1) * (y2 - y1);
  }
}

// ---------------- K10: triangular IoU>0.7 bit matrix (balanced tiles, no div) ----------------
// pred = RN32(inter/uni) > 0.7f  <=>  uni>0 && (double)inter >= T*(double)uni,
// T = midpoint(0.7f, succ(0.7f)) (0.7f mantissa odd -> tie rounds up -> ">=").
// T has 25 sig bits, uni 24 -> T*uni exact in f64: decision is bit-identical.
__global__ __launch_bounds__(256) void k_iou(const float4* __restrict__ sBox,
                                             const float* __restrict__ sAr,
                                             u64* __restrict__ mat) {
  int Bk = blockIdx.x;      // row block: rows [64*Bk, 64*Bk+64)
  int c = blockIdx.y;       // column chunk: words [16c, 16c+16)
  int b = blockIdx.z;
  int wlo = c * 16;
  int whi = wlo + 16 > 94 ? 94 : wlo + 16;
  if (wlo < Bk) wlo = Bk;
  if (wlo >= whi) return;   // tile fully below diagonal
  int tid = threadIdx.x, wv = tid >> 6, lane = tid & 63;
  __shared__ float4 cb[1024];
  __shared__ float ca[1024];
  __shared__ float4 rb[64];
  __shared__ float ra[64];
  const float4* sb = sBox + (size_t)b * TOPK;
  const float* sa = sAr + (size_t)b * TOPK;
  for (int u = tid; u < 1024; u += 256) {
    int j = c * 1024 + u;
    int jc = j < TOPK ? j : TOPK - 1;
    cb[u] = sb[jc];
    ca[u] = sa[jc];
  }
  if (tid < 64) {
    int i = Bk * 64 + tid;
    int ic = i < TOPK ? i : TOPK - 1;
    rb[tid] = sb[ic];
    ra[tid] = sa[ic];
  }
  __syncthreads();
  const double T = (double)0.7f + 0x1p-25;
  size_t matb = (size_t)b * MW;
  for (int g = 0; g < 4; ++g) {
    int r0 = wv * 16 + g * 4;
    float4 r4[4]; float rar[4]; size_t ro[4]; bool rok[4];
    for (int k = 0; k < 4; ++k) {
      int i = Bk * 64 + r0 + k;
      r4[k] = rb[r0 + k];
      rar[k] = ra[r0 + k];
      rok[k] = i < TOPK;
      int rm = i & 63;
      ro[k] = matb + (size_t)(94 * i - (32 * Bk * (Bk - 1) + Bk * rm)) - (size_t)Bk;
    }
    for (int w = wlo; w < whi; ++w) {
      int u = (w - c * 16) * 64 + lane;
      float4 c4 = cb[u];
      float car = ca[u];
#pragma unroll
      for (int k = 0; k < 4; ++k) {
        if (!rok[k]) continue;  // wave-uniform
        float iw = fminf(c4.z, r4[k].z) - fmaxf(c4.x, r4[k].x);
        iw = fmaxf(iw, 0.0f);
        float ih = fminf(c4.w, r4[k].w) - fmaxf(c4.y, r4[k].y);
        ih = fmaxf(ih, 0.0f);
        float inter = iw * ih;
        float uni = (car + rar[k]) - inter;
        bool pred = (uni > 0.0f) && ((double)inter >= T * (double)uni);
        u64 w64 = __ballot(pred);
        if (lane == 0) mat[ro[k] + (size_t)w] = w64;
      }
    }
  }
}

// ---------------- K11: batched-LDS sequential scan + output (1024 thr, coalesced stage) ----------------
__global__ __launch_bounds__(1024) void k_scan(const float4* __restrict__ anchors,
                                               const int* __restrict__ isz,
                                               const float* __restrict__ logits,
                                               const float4* __restrict__ deltas,
                                               const unsigned* __restrict__ sIdx,
                                               const unsigned* __restrict__ sKey,
                                               const u64* __restrict__ mat,
                                               float* __restrict__ out) {
  __shared__ u64 rowbuf[64 * 94];  // 48.1 KB
  __shared__ unsigned keepL[POSTK];
  __shared__ int nkSh;
  int b = blockIdx.x, tid = threadIdx.x, lane = tid & 63, wv = tid >> 6;
  const u64* mb = mat + (size_t)b * MW;
  u64 rm0 = 0, rm1 = 0;  // wave0: lane holds removal words lane and 64+lane
  int nk = 0;
  if (tid == 0) nkSh = 0;
  __syncthreads();
  for (int B = 0; B < 94; ++B) {
    if (nkSh >= POSTK) break;
    int len = 94 - B;
    // wave wv stages rows wv*4..wv*4+3; lanes read contiguous words (coalesced)
    for (int rr = 0; rr < 4; ++rr) {
      int r = wv * 4 + rr;
      int i = B * 64 + r;
      if (i < TOPK) {
        size_t off = (size_t)(94 * i - (32 * B * (B - 1) + B * r));
        u64* dst = &rowbuf[r * 94];
        if (lane < len) dst[lane] = mb[off + lane];
        int w2 = lane + 64;
        if (w2 < len) dst[w2] = mb[off + w2];
      }
    }
    __syncthreads();
    if (wv == 0) {
      int jl = B * 64 + lane;
      unsigned skl = (jl < TOPK) ? sKey[(size_t)b * TOPK + jl] : 0u;
      unsigned nl = (jl < TOPK) ? sIdx[(size_t)b * TOPK + jl] : 0u;
      u64 v64 = __ballot(skl > KEY_NEGHALF);
      u64 cur = (B < 64) ? __shfl(rm0, B) : __shfl(rm1, B - 64);
      u64 alive = v64 & ~cur;
      while (alive && nk < POSTK) {
        int c = __ffsll(alive) - 1;
        unsigned n = __shfl(nl, c);
        if (lane == 0) keepL[nk] = n;
        ++nk;
        u64 w0 = (lane >= B) ? rowbuf[c * 94 + (lane - B)] : 0ull;
        int w1i = 64 + lane;
        u64 w1 = (w1i <= 93 && w1i >= B) ? rowbuf[c * 94 + (w1i - B)] : 0ull;
        rm0 |= w0;
        rm1 |= w1;
        cur = (B < 64) ? __shfl(rm0, B) : __shfl(rm1, B - 64);
        alive = v64 & ~cur;
        alive &= (c >= 63) ? 0ull : (~0ull << (c + 1));
      }
      if (lane == 0) nkSh = nk;
    }
    __syncthreads();  // rowbuf consumed; nkSh visible at loop top
  }
  int nkF = nkSh;
  float H1 = (float)isz[2 * b] - 1.0f;
  float W1 = (float)isz[2 * b + 1] - 1.0f;
  const size_t base = (size_t)b * NN;
  for (int q = tid; q < POSTK; q += 1024) {
    float px1 = 0.f, py1 = 0.f, px2 = 0.f, py2 = 0.f;
    float L = 1e-8f, d0 = 0.f, d1 = 0.f, d2 = 0.f, d3 = 0.f, V = 0.f;
    if (q < nkF) {
      unsigned n = keepL[q];
      float4 a = anchors[base + n];
      float4 d = deltas[base + n];
      float x1, y1, x2, y2; bool valid;
      decode_box(a, d, W1, H1, x1, y1, x2, y2, valid);
      px1 = x1; py1 = y1; px2 = x2; py2 = y2;
      L = logits[base + n];
      d0 = d.x; d1 = d.y; d2 = d.z; d3 = d.w;
      V = 1.0f;
    }
    size_t row = (size_t)b * POSTK + q;
    float* outP = out + row * 4;
    outP[0] = px1; outP[1] = py1; outP[2] = px2; outP[3] = py2;
    out[(size_t)BN * POSTK * 4 + row] = L;
    float* outD = out + (size_t)BN * POSTK * 5 + row * 4;
    outD[0] = d0; outD[1] = d1; outD[2] = d2; outD[3] = d3;
    out[(size_t)BN * POSTK * 9 + row] = V;
  }
}

extern "C" void kernel_launch(void* const* d_in, const int* in_sizes, int n_in,
                              void* d_out, int out_size, void* d_ws, size_t ws_size,
                              hipStream_t stream) {
  const float4* anchors = (const float4*)d_in[0];
  const int* isz = (const int*)d_in[1];
  const float* logits = (const float*)d_in[2];
  const float4* deltas = (const float4*)d_in[3];
  float* out = (float*)d_out;

  // Workspace layout (u32 units). The bit matrix (36.6 MB) aliases the
  // histogram/keys region — all of it is dead before k_iou writes.
  unsigned* W = (unsigned*)d_ws;
  unsigned* hist1 = W;                       // 16*65536
  unsigned* keys = W + 1048576;              // 16*200000
  unsigned* hist0 = W + 4248576;             // 16*8*256 (8 shards/image)
  unsigned* hist2 = W + 4281344;             // 16*256
  unsigned* cntGt = W + 4285440;             // 16*64 (one cache line per image)
  unsigned* meta = W + 4286464;              // 16*8
  u64* mat = (u64*)d_ws;                     // 16*MW u64 = 36.58 MB (aliases above)
  unsigned* T = W + 9143808;                 // tail (non-aliased)
  unsigned* sel = T;                         // 16*6000
  unsigned* sIdx = T + 96000;                // 16*6000
  unsigned* sKey = T + 192000;               // 16*6000
  float4* sBox = (float4*)(T + 288000);      // 16*6000 float4
  float* sAr = (float*)(T + 672000);         // 16*6000  (total ws ~39.7 MB)

  hipMemsetAsync(hist1, 0, (size_t)1048576 * 4, stream);
  hipMemsetAsync(hist0, 0, (size_t)(32768 + 4096 + 1024 + 128) * 4, stream);

  dim3 gN((NN + 255) / 256, BN);
  k_score<<<gN, 256, 0, stream>>>(anchors, isz, logits, deltas, keys, hist0);
  k_sel0<<<BN, 256, 0, stream>>>(hist0, meta);
  k_h1<<<gN, 256, 0, stream>>>(keys, meta, hist1);
  k_sel1<<<BN, 256, 0, stream>>>(hist1, meta);
  k_h2<<<gN, 256, 0, stream>>>(keys, meta, hist2);
  k_sel2<<<BN, 256, 0, stream>>>(hist2, meta);
  k_compact<<<dim3(25, BN), 256, 0, stream>>>(keys, meta, cntGt, sel);
  k_resolve<<<BN, 256, 0, stream>>>(keys, meta, sel);
  k_sort<<<BN, 1024, 0, stream>>>(anchors, isz, keys, deltas, sel, sIdx, sKey, sBox, sAr);
  k_iou<<<dim3(94, 6, BN), 256, 0, stream>>>(sBox, sAr, mat);
  k_scan<<<BN, 1024, 0, stream>>>(anchors, isz, logits, deltas, sIdx, sKey, mat, out);
}

// Round 5
// 875.544 us; speedup vs baseline: 6.1761x; 1.1532x over previous
//
#include <hip/hip_runtime.h>

#define BN 16
#define NN 200000
#define TOPK 6000
#define POSTK 1000
#define MW 285744               /* triangular matrix u64-words per image */
#define KEY_NEGHALF 0x40FFFFFFu /* key_of(-0.5f); valid <=> key > this */

// Decision-critical math must match CPU reference bit-for-bit: no FMA contraction.
#pragma clang fp contract(off)

typedef unsigned long long u64;

__device__ __forceinline__ float exp_cr(float x) {
  return (float)exp((double)x);  // correctly-rounded f32 exp via double
}

__device__ __forceinline__ unsigned key_of(float s) {
  unsigned u = __float_as_uint(s);
  return (u & 0x80000000u) ? ~u : (u | 0x80000000u);
}

__device__ __forceinline__ void decode_box(float4 a, float4 d, float W1, float H1,
                                           float& x1, float& y1, float& x2, float& y2,
                                           bool& valid) {
  float aw = a.z - a.x;
  float ah = a.w - a.y;
  float ax = a.x + 0.5f * aw;
  float ay = a.y + 0.5f * ah;
  float px = ax + d.x * aw;
  float py = ay + d.y * ah;
  float cz = fminf(fmaxf(d.z, -10.0f), 10.0f);
  float cw = fminf(fmaxf(d.w, -10.0f), 10.0f);
  float pw = aw * exp_cr(cz);
  float ph = ah * exp_cr(cw);
  x1 = fminf(fmaxf(px - 0.5f * pw, 0.0f), W1);
  y1 = fminf(fmaxf(py - 0.5f * ph, 0.0f), H1);
  x2 = fminf(fmaxf(px + 0.5f * pw, 0.0f), W1);
  y2 = fminf(fmaxf(py + 0.5f * ph, 0.0f), H1);
  valid = ((x2 - x1) >= 16.0f) && ((y2 - y1) >= 16.0f);
}

__device__ __forceinline__ float score_of(float lg, bool valid) {
  float e = exp_cr(-lg);
  float s = 1.0f / (1.0f + e);
  return valid ? s : -1.0f;
}

// ---------------- K1: keys + wave-aggregated LDS histogram + sharded merge ----------------
__global__ __launch_bounds__(256) void k_score(const float4* __restrict__ anchors,
                                               const int* __restrict__ isz,
                                               const float* __restrict__ logits,
                                               const float4* __restrict__ deltas,
                                               unsigned* __restrict__ keys,
                                               unsigned* __restrict__ hist0) {
  __shared__ unsigned h[256];
  int b = blockIdx.y;
  int idx = blockIdx.x * 256 + threadIdx.x;
  int lane = threadIdx.x & 63;
  h[threadIdx.x] = 0;
  __syncthreads();
  unsigned bin = 0;
  bool active = idx < NN;
  if (active) {
    size_t i = (size_t)b * NN + idx;
    float4 a = anchors[i];
    float4 d = deltas[i];
    float H1 = (float)isz[2 * b] - 1.0f;
    float W1 = (float)isz[2 * b + 1] - 1.0f;
    float x1, y1, x2, y2; bool valid;
    decode_box(a, d, W1, H1, x1, y1, x2, y2, valid);
    float sc = score_of(logits[i], valid);
    unsigned key = key_of(sc);
    keys[i] = key;
    bin = key >> 24;
  }
  // match-any aggregation: one LDS atomic per distinct bin per wave (~3 typical)
  u64 act = __ballot(active);
  while (act) {
    int l = __ffsll(act) - 1;
    unsigned vb = __shfl(bin, l);
    u64 same = __ballot(bin == vb) & act;
    if (lane == l) atomicAdd(&h[vb], (unsigned)__popcll(same));
    act &= ~same;
  }
  __syncthreads();
  unsigned c = h[threadIdx.x];
  if (c) atomicAdd(&hist0[((size_t)b * 8 + (blockIdx.x & 7)) * 256 + threadIdx.x], c);
}

// ---------------- K2: top byte bin (sum 8 shards) ----------------
__global__ void k_sel0(const unsigned* __restrict__ hist0, unsigned* __restrict__ meta) {
  int b = blockIdx.x, t = threadIdx.x;
  __shared__ unsigned c[256];
  unsigned s = 0;
  for (int sh = 0; sh < 8; ++sh) s += hist0[((size_t)b * 8 + sh) * 256 + t];
  c[t] = s;
  __syncthreads();
  if (t == 0) {
    unsigned cum = 0;
    for (int u = 255; u >= 0; --u) {
      if (cum + c[u] >= TOPK) { meta[b * 8 + 0] = (unsigned)u; meta[b * 8 + 1] = cum; break; }
      cum += c[u];
    }
  }
}

// ---------------- K3: mid-16-bit histogram within byte bin ----------------
__global__ __launch_bounds__(256) void k_h1(const unsigned* __restrict__ keys,
                                            const unsigned* __restrict__ meta,
                                            unsigned* __restrict__ hist1) {
  int b = blockIdx.y;
  int idx = blockIdx.x * 256 + threadIdx.x;
  if (idx >= NN) return;
  unsigned key = keys[(size_t)b * NN + idx];
  unsigned B0 = meta[b * 8 + 0];
  if ((key >> 24) == B0)
    atomicAdd(&hist1[(size_t)b * 65536 + ((key >> 8) & 0xFFFFu)], 1u);
}

// ---------------- K4: find mid-16-bit value ----------------
__global__ void k_sel1(const unsigned* __restrict__ hist1, unsigned* __restrict__ meta) {
  int b = blockIdx.x, t = threadIdx.x;
  __shared__ unsigned part[256];
  __shared__ unsigned above[256];
  const unsigned* h = hist1 + (size_t)b * 65536;
  unsigned cA0 = meta[b * 8 + 1];
  unsigned R1 = TOPK - cA0;
  int base = t * 256;
  unsigned sum = 0;
  for (int j = 0; j < 256; ++j) sum += h[base + j];
  part[t] = sum;
  __syncthreads();
  if (t == 0) {
    unsigned run = 0;
    for (int u = 255; u >= 0; --u) { above[u] = run; run += part[u]; }
  }
  __syncthreads();
  unsigned ab = above[t];
  if (ab < R1 && ab + part[t] >= R1) {
    unsigned cum = ab;
    for (int j = 255; j >= 0; --j) {
      unsigned c = h[base + j];
      if (cum + c >= R1) {
        meta[b * 8 + 2] = (unsigned)(base + j);
        meta[b * 8 + 3] = cA0 + cum;
        break;
      }
      cum += c;
    }
  }
}

// ---------------- K5: low-byte histogram within 24-bit prefix ----------------
__global__ __launch_bounds__(256) void k_h2(const unsigned* __restrict__ keys,
                                            const unsigned* __restrict__ meta,
                                            unsigned* __restrict__ hist2) {
  int b = blockIdx.y;
  int idx = blockIdx.x * 256 + threadIdx.x;
  if (idx >= NN) return;
  unsigned key = keys[(size_t)b * NN + idx];
  unsigned pref = (meta[b * 8 + 0] << 16) | meta[b * 8 + 2];
  if ((key >> 8) == pref)
    atomicAdd(&hist2[b * 256 + (key & 0xFFu)], 1u);
}

// ---------------- K6: exact threshold key ----------------
__global__ void k_sel2(const unsigned* __restrict__ hist2, unsigned* __restrict__ meta) {
  int b = blockIdx.x, t = threadIdx.x;
  __shared__ unsigned c[256];
  c[t] = hist2[b * 256 + t];
  __syncthreads();
  if (t == 0) {
    unsigned R2 = TOPK - meta[b * 8 + 3];
    unsigned cum = 0;
    for (int u = 255; u >= 0; --u) {
      if (cum + c[u] >= R2) {
        unsigned K = (meta[b * 8 + 0] << 24) | (meta[b * 8 + 2] << 8) | (unsigned)u;
        unsigned nG = meta[b * 8 + 3] + cum;
        meta[b * 8 + 4] = K;
        meta[b * 8 + 5] = nG;
        meta[b * 8 + 6] = TOPK - nG;
        break;
      }
      cum += c[u];
    }
  }
}

// ---------------- K7: compact strictly-greater (one atomic per block) ----------------
__global__ __launch_bounds__(256) void k_compact(const unsigned* __restrict__ keys,
                                                 const unsigned* __restrict__ meta,
                                                 unsigned* __restrict__ cntGt,
                                                 unsigned* __restrict__ sel) {
  __shared__ unsigned sc[256];
  __shared__ unsigned baseSh;
  int b = blockIdx.y, tid = threadIdx.x;
  const unsigned* kb = keys + (size_t)b * NN;
  unsigned K = meta[b * 8 + 4];
  int start = blockIdx.x * 8000;
  int end = start + 8000 < NN ? start + 8000 : NN;
  unsigned cnt = 0;
  for (int n = start + tid; n < end; n += 256) cnt += (kb[n] > K);
  sc[tid] = cnt;
  __syncthreads();
  if (tid == 0) {
    unsigned run = 0;
    for (int u = 0; u < 256; ++u) { unsigned v = sc[u]; sc[u] = run; run += v; }
    baseSh = run ? atomicAdd(&cntGt[b * 64], run) : 0u;
  }
  __syncthreads();
  unsigned pos = baseSh + sc[tid];
  for (int n = start + tid; n < end; n += 256)
    if (kb[n] > K) sel[(size_t)b * TOPK + pos++] = (unsigned)n;
}

// ---------------- K8: boundary ties -> smallest original indices ----------------
__global__ void k_resolve(const unsigned* __restrict__ keys, const unsigned* __restrict__ meta,
                          unsigned* __restrict__ sel) {
  int b = blockIdx.x, t = threadIdx.x;  // 256 threads
  __shared__ unsigned cnt[256];
  unsigned K = meta[b * 8 + 4], nG = meta[b * 8 + 5], nE = meta[b * 8 + 6];
  const unsigned* kb = keys + (size_t)b * NN;
  const int CH = (NN + 255) / 256;
  int lo = t * CH;
  int hi = lo + CH < NN ? lo + CH : NN;
  unsigned c = 0;
  for (int n = lo; n < hi; ++n) c += (kb[n] == K);
  cnt[t] = c;
  __syncthreads();
  if (t == 0) {
    unsigned run = 0;
    for (int u = 0; u < 256; ++u) { unsigned v = cnt[u]; cnt[u] = run; run += v; }
  }
  __syncthreads();
  unsigned r = cnt[t];
  for (int n = lo; n < hi && r < nE; ++n)
    if (kb[n] == K) { sel[(size_t)b * TOPK + nG + r] = (unsigned)n; ++r; }
}

// ---------------- K9: bitonic sort 6000 candidates by (score desc, idx asc) ----------------
__global__ __launch_bounds__(1024) void k_sort(const float4* __restrict__ anchors,
                                               const int* __restrict__ isz,
                                               const unsigned* __restrict__ keys,
                                               const float4* __restrict__ deltas,
                                               const unsigned* __restrict__ sel,
                                               unsigned* __restrict__ sIdx,
                                               unsigned* __restrict__ sKey,
                                               float4* __restrict__ sBox,
                                               float* __restrict__ sAr) {
  __shared__ u64 skey[8192];  // 64 KB
  int b = blockIdx.x, tid = threadIdx.x;
  for (int p = tid; p < 8192; p += 1024) {
    u64 kk = 0;
    if (p < TOPK) {
      unsigned n = sel[(size_t)b * TOPK + p];
      kk = ((u64)keys[(size_t)b * NN + n] << 32) | (unsigned)(NN - 1 - (int)n);
    }
    skey[p] = kk;
  }
  __syncthreads();
  for (unsigned k = 2; k <= 8192; k <<= 1) {
    for (unsigned j = k >> 1; j > 0; j >>= 1) {
      for (unsigned p = tid; p < 4096; p += 1024) {
        unsigned i = ((p & ~(j - 1)) << 1) | (p & (j - 1));
        unsigned x = i | j;
        u64 a = skey[i], c = skey[x];
        bool desc = ((i & k) == 0);
        if (desc ? (a < c) : (a > c)) { skey[i] = c; skey[x] = a; }
      }
      __syncthreads();
    }
  }
  float H1 = (float)isz[2 * b] - 1.0f;
  float W1 = (float)isz[2 * b + 1] - 1.0f;
  for (int i = tid; i < TOPK; i += 1024) {
    u64 kk = skey[i];
    unsigned n = (unsigned)(NN - 1) - (unsigned)(kk & 0xFFFFFFFFull);
    sIdx[(size_t)b * TOPK + i] = n;
    sKey[(size_t)b * TOPK + i] = (unsigned)(kk >> 32);
    float4 a = anchors[(size_t)b * NN + n];
    float4 d = deltas[(size_t)b * NN + n];
    float x1, y1, x2, y2; bool valid;
    decode_box(a, d, W1, H1, x1, y1, x2, y2, valid);
    sBox[(size_t)b * TOPK + i] = make_float4(x1, y1, x2, y2);
    sAr[(size_t)b * TOPK + i] = (x2 - x1) * (y2 - y1);
  }
}

// ---------------- K10: triangular IoU>0.7 bit matrix (balanced tiles, no div) ----------------
// pred = RN32(inter/uni) > 0.7f  <=>  uni>0 && (double)inter >= T*(double)uni,
// T = midpoint(0.7f, succ(0.7f)) (0.7f mantissa odd -> tie rounds up -> ">=").
// T has 25 sig bits, uni 24 -> T*uni exact in f64: decision is bit-identical.
__global__ __launch_bounds__(256) void k_iou(const float4* __restrict__ sBox,
                                             const float* __restrict__ sAr,
                                             u64* __restrict__ mat) {
  int Bk = blockIdx.x;      // row block: rows [64*Bk, 64*Bk+64)
  int c = blockIdx.y;       // column chunk: words [16c, 16c+16)
  int b = blockIdx.z;
  int wlo = c * 16;
  int whi = wlo + 16 > 94 ? 94 : wlo + 16;
  if (wlo < Bk) wlo = Bk;
  if (wlo >= whi) return;   // tile fully below diagonal
  int tid = threadIdx.x, wv = tid >> 6, lane = tid & 63;
  __shared__ float4 cb[1024];
  __shared__ float ca[1024];
  __shared__ float4 rb[64];
  __shared__ float ra[64];
  const float4* sb = sBox + (size_t)b * TOPK;
  const float* sa = sAr + (size_t)b * TOPK;
  for (int u = tid; u < 1024; u += 256) {
    int j = c * 1024 + u;
    int jc = j < TOPK ? j : TOPK - 1;
    cb[u] = sb[jc];
    ca[u] = sa[jc];
  }
  if (tid < 64) {
    int i = Bk * 64 + tid;
    int ic = i < TOPK ? i : TOPK - 1;
    rb[tid] = sb[ic];
    ra[tid] = sa[ic];
  }
  __syncthreads();
  const double T = (double)0.7f + 0x1p-25;
  size_t matb = (size_t)b * MW;
  for (int g = 0; g < 4; ++g) {
    int r0 = wv * 16 + g * 4;
    float4 r4[4]; float rar[4]; size_t ro[4]; bool rok[4];
    for (int k = 0; k < 4; ++k) {
      int i = Bk * 64 + r0 + k;
      r4[k] = rb[r0 + k];
      rar[k] = ra[r0 + k];
      rok[k] = i < TOPK;
      int rm = i & 63;
      ro[k] = matb + (size_t)(94 * i - (32 * Bk * (Bk - 1) + Bk * rm)) - (size_t)Bk;
    }
    for (int w = wlo; w < whi; ++w) {
      int u = (w - c * 16) * 64 + lane;
      float4 c4 = cb[u];
      float car = ca[u];
#pragma unroll
      for (int k = 0; k < 4; ++k) {
        if (!rok[k]) continue;  // wave-uniform
        float iw = fminf(c4.z, r4[k].z) - fmaxf(c4.x, r4[k].x);
        iw = fmaxf(iw, 0.0f);
        float ih = fminf(c4.w, r4[k].w) - fmaxf(c4.y, r4[k].y);
        ih = fmaxf(ih, 0.0f);
        float inter = iw * ih;
        float uni = (car + rar[k]) - inter;
        bool pred = (uni > 0.0f) && ((double)inter >= T * (double)uni);
        u64 w64 = __ballot(pred);
        if (lane == 0) mat[ro[k] + (size_t)w] = w64;
      }
    }
  }
}

// ---------------- K11: pick-driven scan ----------------
// Per 64-candidate batch: wave0 keeps the 64 diagonal words (within-batch
// suppression) in registers -> each pick is ffs + one 64-bit shuffle (~60cy
// chain, no memory). Cross-batch suppression: waves 2..15 OR the PICKED rows'
// remaining words (read straight from L2/L3, latency-pipelined 8 thr/word)
// into rmW[94] in LDS after picks are published. Wave1 prefetches the next
// batch's diag/key/idx during the pick loop.
__global__ __launch_bounds__(1024) void k_scan(const float4* __restrict__ anchors,
                                               const int* __restrict__ isz,
                                               const float* __restrict__ logits,
                                               const float4* __restrict__ deltas,
                                               const unsigned* __restrict__ sIdx,
                                               const unsigned* __restrict__ sKey,
                                               const u64* __restrict__ mat,
                                               float* __restrict__ out) {
  __shared__ u64 rmW[94];
  __shared__ u64 diagb[2][64];
  __shared__ unsigned keyb[2][64];
  __shared__ unsigned idxb[2][64];
  __shared__ unsigned keepL[POSTK];
  __shared__ unsigned picksList[64];
  __shared__ int nkSh, npicksSh, allInvSh;
  int b = blockIdx.x, tid = threadIdx.x, lane = tid & 63, wv = tid >> 6;
  const u64* mb = mat + (size_t)b * MW;
  const size_t bT = (size_t)b * TOPK;
  if (tid < 94) rmW[tid] = 0;
  if (tid == 0) { nkSh = 0; allInvSh = 0; }
  if (wv == 1) {  // prefetch batch 0 (rows 0..63: diag word is rowOff(i)+0 = 94*i)
    diagb[0][lane] = mb[(size_t)(94 * lane)];
    keyb[0][lane] = sKey[bT + lane];
    idxb[0][lane] = sIdx[bT + lane];
  }
  __syncthreads();
  for (int B = 0; B < 94; ++B) {
    if (nkSh >= POSTK || allInvSh) break;  // uniform (LDS) -> no divergence
    int par = B & 1;
    if (wv == 0) {
      unsigned skl = keyb[par][lane];
      unsigned nl = idxb[par][lane];
      u64 w0 = diagb[par][lane];
      u64 v64 = __ballot(skl > KEY_NEGHALF);
      int base = nkSh;
      u64 alive = v64 & ~rmW[B];
      u64 picks = 0;
      int cnt = 0, lim = POSTK - base;
      while (alive && cnt < lim) {
        int c = __ffsll(alive) - 1;
        picks |= 1ull << c;
        ++cnt;
        u64 sup = __shfl(w0, c);   // row c's within-batch suppression word
        alive &= ~sup;
        alive &= ~((2ull << c) - 1ull);  // clear bits <= c (c=63 wraps to all-ones)
      }
      int rank = __popcll(picks & ((1ull << lane) - 1ull));
      if ((picks >> lane) & 1ull) {
        keepL[base + rank] = nl;       // pick order == ascending lane == argmax order
        picksList[rank] = (unsigned)lane;
      }
      if (lane == 0) { npicksSh = cnt; nkSh = base + cnt; allInvSh = (v64 == 0); }
    } else if (wv == 1) {
      int nb = B + 1;
      if (nb < 94) {
        int i2 = nb * 64 + lane;
        if (i2 < TOPK) {
          int off2 = 94 * i2 - 32 * nb * (nb - 1) - nb * lane;  // rowOff(i2), word nb is first
          diagb[nb & 1][lane] = mb[(size_t)off2];
          keyb[nb & 1][lane] = sKey[bT + i2];
          idxb[nb & 1][lane] = sIdx[bT + i2];
        } else {
          diagb[nb & 1][lane] = 0;
          keyb[nb & 1][lane] = 0;
          idxb[nb & 1][lane] = 0;
        }
      }
    }
    __syncthreads();  // picks/npicks published; prefetch landed
    int np = npicksSh;
    if (tid >= 128 && np > 0) {
      int t = tid - 128;
      int w = B + 1 + (t >> 3);  // word index; 8 threads per word
      int k = t & 3;             // (t>>3) in [0,112): covers w up to B+112
      k = t & 7;
      if (w < 94) {
        int base94 = 6016 * B - 32 * B * (B - 1);  // rowOff(B*64)
        int span = 94 - B;                          // row length; rowOff(B*64+c)=base94+span*c
        u64 a0 = 0, a1 = 0;
        int j = k;
        for (; j + 8 < np; j += 16) {  // two independent load chains
          a0 |= mb[(size_t)(base94 + span * (int)picksList[j] + (w - B))];
          a1 |= mb[(size_t)(base94 + span * (int)picksList[j + 8] + (w - B))];
        }
        if (j < np) a0 |= mb[(size_t)(base94 + span * (int)picksList[j] + (w - B))];
        a0 |= a1;
        if (a0) atomicOr(&rmW[w], a0);
      }
    }
    __syncthreads();  // rmW final for batch B+1
  }
  int nkF = nkSh;
  float H1 = (float)isz[2 * b] - 1.0f;
  float W1 = (float)isz[2 * b + 1] - 1.0f;
  const size_t base = (size_t)b * NN;
  for (int q = tid; q < POSTK; q += 1024) {
    float px1 = 0.f, py1 = 0.f, px2 = 0.f, py2 = 0.f;
    float L = 1e-8f, d0 = 0.f, d1 = 0.f, d2 = 0.f, d3 = 0.f, V = 0.f;
    if (q < nkF) {
      unsigned n = keepL[q];
      float4 a = anchors[base + n];
      float4 d = deltas[base + n];
      float x1, y1, x2, y2; bool valid;
      decode_box(a, d, W1, H1, x1, y1, x2, y2, valid);
      px1 = x1; py1 = y1; px2 = x2; py2 = y2;
      L = logits[base + n];
      d0 = d.x; d1 = d.y; d2 = d.z; d3 = d.w;
      V = 1.0f;
    }
    size_t row = (size_t)b * POSTK + q;
    float* outP = out + row * 4;
    outP[0] = px1; outP[1] = py1; outP[2] = px2; outP[3] = py2;
    out[(size_t)BN * POSTK * 4 + row] = L;
    float* outD = out + (size_t)BN * POSTK * 5 + row * 4;
    outD[0] = d0; outD[1] = d1; outD[2] = d2; outD[3] = d3;
    out[(size_t)BN * POSTK * 9 + row] = V;
  }
}

extern "C" void kernel_launch(void* const* d_in, const int* in_sizes, int n_in,
                              void* d_out, int out_size, void* d_ws, size_t ws_size,
                              hipStream_t stream) {
  const float4* anchors = (const float4*)d_in[0];
  const int* isz = (const int*)d_in[1];
  const float* logits = (const float*)d_in[2];
  const float4* deltas = (const float4*)d_in[3];
  float* out = (float*)d_out;

  // Workspace layout (u32 units). The bit matrix (36.6 MB) aliases the
  // histogram/keys region — all of it is dead before k_iou writes.
  unsigned* W = (unsigned*)d_ws;
  unsigned* hist1 = W;                       // 16*65536
  unsigned* keys = W + 1048576;              // 16*200000
  unsigned* hist0 = W + 4248576;             // 16*8*256 (8 shards/image)
  unsigned* hist2 = W + 4281344;             // 16*256
  unsigned* cntGt = W + 4285440;             // 16*64 (one cache line per image)
  unsigned* meta = W + 4286464;              // 16*8
  u64* mat = (u64*)d_ws;                     // 16*MW u64 = 36.58 MB (aliases above)
  unsigned* T = W + 9143808;                 // tail (non-aliased)
  unsigned* sel = T;                         // 16*6000
  unsigned* sIdx = T + 96000;                // 16*6000
  unsigned* sKey = T + 192000;               // 16*6000
  float4* sBox = (float4*)(T + 288000);      // 16*6000 float4
  float* sAr = (float*)(T + 672000);         // 16*6000  (total ws ~39.7 MB)

  hipMemsetAsync(hist1, 0, (size_t)1048576 * 4, stream);
  hipMemsetAsync(hist0, 0, (size_t)(32768 + 4096 + 1024 + 128) * 4, stream);

  dim3 gN((NN + 255) / 256, BN);
  k_score<<<gN, 256, 0, stream>>>(anchors, isz, logits, deltas, keys, hist0);
  k_sel0<<<BN, 256, 0, stream>>>(hist0, meta);
  k_h1<<<gN, 256, 0, stream>>>(keys, meta, hist1);
  k_sel1<<<BN, 256, 0, stream>>>(hist1, meta);
  k_h2<<<gN, 256, 0, stream>>>(keys, meta, hist2);
  k_sel2<<<BN, 256, 0, stream>>>(hist2, meta);
  k_compact<<<dim3(25, BN), 256, 0, stream>>>(keys, meta, cntGt, sel);
  k_resolve<<<BN, 256, 0, stream>>>(keys, meta, sel);
  k_sort<<<BN, 1024, 0, stream>>>(anchors, isz, keys, deltas, sel, sIdx, sKey, sBox, sAr);
  k_iou<<<dim3(94, 6, BN), 256, 0, stream>>>(sBox, sAr, mat);
  k_scan<<<BN, 1024, 0, stream>>>(anchors, isz, logits, deltas, sIdx, sKey, mat, out);
}

// Round 6
// 643.179 us; speedup vs baseline: 8.4074x; 1.3613x over previous
//
#include <hip/hip_runtime.h>

#define BN 16
#define NN 200000
#define TOPK 6000
#define POSTK 1000
#define MW 285744               /* triangular matrix u64-words per image */
#define KEY_NEGHALF 0x40FFFFFFu /* key_of(-0.5f); valid <=> key > this */
#define EQCAP 8192              /* max boundary ties tracked per image */

// Decision-critical math must match CPU reference bit-for-bit: no FMA contraction.
#pragma clang fp contract(off)

typedef unsigned long long u64;

__device__ __forceinline__ float exp_cr(float x) {
  return (float)exp((double)x);  // correctly-rounded f32 exp via double
}

__device__ __forceinline__ unsigned key_of(float s) {
  unsigned u = __float_as_uint(s);
  return (u & 0x80000000u) ? ~u : (u | 0x80000000u);
}

__device__ __forceinline__ void decode_box(float4 a, float4 d, float W1, float H1,
                                           float& x1, float& y1, float& x2, float& y2,
                                           bool& valid) {
  float aw = a.z - a.x;
  float ah = a.w - a.y;
  float ax = a.x + 0.5f * aw;
  float ay = a.y + 0.5f * ah;
  float px = ax + d.x * aw;
  float py = ay + d.y * ah;
  float cz = fminf(fmaxf(d.z, -10.0f), 10.0f);
  float cw = fminf(fmaxf(d.w, -10.0f), 10.0f);
  float pw = aw * exp_cr(cz);
  float ph = ah * exp_cr(cw);
  x1 = fminf(fmaxf(px - 0.5f * pw, 0.0f), W1);
  y1 = fminf(fmaxf(py - 0.5f * ph, 0.0f), H1);
  x2 = fminf(fmaxf(px + 0.5f * pw, 0.0f), W1);
  y2 = fminf(fmaxf(py + 0.5f * ph, 0.0f), H1);
  valid = ((x2 - x1) >= 16.0f) && ((y2 - y1) >= 16.0f);
}

__device__ __forceinline__ float score_of(float lg, bool valid) {
  float e = exp_cr(-lg);
  float s = 1.0f / (1.0f + e);
  return valid ? s : -1.0f;
}

// ---------------- K1: keys + wave-aggregated LDS histogram + sharded merge ----------------
__global__ __launch_bounds__(256) void k_score(const float4* __restrict__ anchors,
                                               const int* __restrict__ isz,
                                               const float* __restrict__ logits,
                                               const float4* __restrict__ deltas,
                                               unsigned* __restrict__ keys,
                                               unsigned* __restrict__ hist0) {
  __shared__ unsigned h[256];
  int b = blockIdx.y;
  int idx = blockIdx.x * 256 + threadIdx.x;
  int lane = threadIdx.x & 63;
  h[threadIdx.x] = 0;
  __syncthreads();
  unsigned bin = 0;
  bool active = idx < NN;
  if (active) {
    size_t i = (size_t)b * NN + idx;
    float4 a = anchors[i];
    float4 d = deltas[i];
    float H1 = (float)isz[2 * b] - 1.0f;
    float W1 = (float)isz[2 * b + 1] - 1.0f;
    float x1, y1, x2, y2; bool valid;
    decode_box(a, d, W1, H1, x1, y1, x2, y2, valid);
    float sc = score_of(logits[i], valid);
    unsigned key = key_of(sc);
    keys[i] = key;
    bin = key >> 24;
  }
  // match-any aggregation: one LDS atomic per distinct bin per wave (~3 typical)
  u64 act = __ballot(active);
  while (act) {
    int l = __ffsll(act) - 1;
    unsigned vb = __shfl(bin, l);
    u64 same = __ballot(bin == vb) & act;
    if (lane == l) atomicAdd(&h[vb], (unsigned)__popcll(same));
    act &= ~same;
  }
  __syncthreads();
  unsigned c = h[threadIdx.x];
  if (c) atomicAdd(&hist0[((size_t)b * 8 + (blockIdx.x & 7)) * 256 + threadIdx.x], c);
}

// ---------------- K2: top byte bin (sum 8 shards) ----------------
__global__ void k_sel0(const unsigned* __restrict__ hist0, unsigned* __restrict__ meta) {
  int b = blockIdx.x, t = threadIdx.x;
  __shared__ unsigned c[256];
  unsigned s = 0;
  for (int sh = 0; sh < 8; ++sh) s += hist0[((size_t)b * 8 + sh) * 256 + t];
  c[t] = s;
  __syncthreads();
  if (t == 0) {
    unsigned cum = 0;
    for (int u = 255; u >= 0; --u) {
      if (cum + c[u] >= TOPK) { meta[b * 8 + 0] = (unsigned)u; meta[b * 8 + 1] = cum; break; }
      cum += c[u];
    }
  }
}

// ---------------- K3: mid-16-bit histogram within byte bin ----------------
__global__ __launch_bounds__(256) void k_h1(const unsigned* __restrict__ keys,
                                            const unsigned* __restrict__ meta,
                                            unsigned* __restrict__ hist1) {
  int b = blockIdx.y;
  int idx = blockIdx.x * 256 + threadIdx.x;
  if (idx >= NN) return;
  unsigned key = keys[(size_t)b * NN + idx];
  unsigned B0 = meta[b * 8 + 0];
  if ((key >> 24) == B0)
    atomicAdd(&hist1[(size_t)b * 65536 + ((key >> 8) & 0xFFFFu)], 1u);
}

// ---------------- K4: find mid-16-bit value ----------------
__global__ void k_sel1(const unsigned* __restrict__ hist1, unsigned* __restrict__ meta) {
  int b = blockIdx.x, t = threadIdx.x;
  __shared__ unsigned part[256];
  __shared__ unsigned above[256];
  const unsigned* h = hist1 + (size_t)b * 65536;
  unsigned cA0 = meta[b * 8 + 1];
  unsigned R1 = TOPK - cA0;
  int base = t * 256;
  unsigned sum = 0;
  for (int j = 0; j < 256; ++j) sum += h[base + j];
  part[t] = sum;
  __syncthreads();
  if (t == 0) {
    unsigned run = 0;
    for (int u = 255; u >= 0; --u) { above[u] = run; run += part[u]; }
  }
  __syncthreads();
  unsigned ab = above[t];
  if (ab < R1 && ab + part[t] >= R1) {
    unsigned cum = ab;
    for (int j = 255; j >= 0; --j) {
      unsigned c = h[base + j];
      if (cum + c >= R1) {
        meta[b * 8 + 2] = (unsigned)(base + j);
        meta[b * 8 + 3] = cA0 + cum;
        break;
      }
      cum += c;
    }
  }
}

// ---------------- K5: low-byte histogram within 24-bit prefix ----------------
__global__ __launch_bounds__(256) void k_h2(const unsigned* __restrict__ keys,
                                            const unsigned* __restrict__ meta,
                                            unsigned* __restrict__ hist2) {
  int b = blockIdx.y;
  int idx = blockIdx.x * 256 + threadIdx.x;
  if (idx >= NN) return;
  unsigned key = keys[(size_t)b * NN + idx];
  unsigned pref = (meta[b * 8 + 0] << 16) | meta[b * 8 + 2];
  if ((key >> 8) == pref)
    atomicAdd(&hist2[b * 256 + (key & 0xFFu)], 1u);
}

// ---------------- K6: exact threshold key ----------------
__global__ void k_sel2(const unsigned* __restrict__ hist2, unsigned* __restrict__ meta) {
  int b = blockIdx.x, t = threadIdx.x;
  __shared__ unsigned c[256];
  c[t] = hist2[b * 256 + t];
  __syncthreads();
  if (t == 0) {
    unsigned R2 = TOPK - meta[b * 8 + 3];
    unsigned cum = 0;
    for (int u = 255; u >= 0; --u) {
      if (cum + c[u] >= R2) {
        unsigned K = (meta[b * 8 + 0] << 24) | (meta[b * 8 + 2] << 8) | (unsigned)u;
        unsigned nG = meta[b * 8 + 3] + cum;
        meta[b * 8 + 4] = K;
        meta[b * 8 + 5] = nG;
        meta[b * 8 + 6] = TOPK - nG;
        break;
      }
      cum += c[u];
    }
  }
}

// ---------------- K7: compact strictly-greater + collect boundary ties ----------------
// One padded atomic per block for positions; ties (key==K, rare) go to an
// unordered per-image list (k_resolve2 ranks them). Replaces the 245us
// uncoalesced 16-block k_resolve scan with work fused into this kernel's
// already-coalesced pass.
__global__ __launch_bounds__(256) void k_compact(const unsigned* __restrict__ keys,
                                                 const unsigned* __restrict__ meta,
                                                 unsigned* __restrict__ cntGt,
                                                 unsigned* __restrict__ sel,
                                                 unsigned* __restrict__ cntEq,
                                                 unsigned* __restrict__ eq) {
  __shared__ unsigned sc[256];
  __shared__ unsigned baseSh;
  int b = blockIdx.y, tid = threadIdx.x;
  const unsigned* kb = keys + (size_t)b * NN;
  unsigned K = meta[b * 8 + 4];
  int start = blockIdx.x * 8000;
  int end = start + 8000 < NN ? start + 8000 : NN;
  unsigned cnt = 0;
  for (int n = start + tid; n < end; n += 256) cnt += (kb[n] > K);
  sc[tid] = cnt;
  __syncthreads();
  if (tid == 0) {
    unsigned run = 0;
    for (int u = 0; u < 256; ++u) { unsigned v = sc[u]; sc[u] = run; run += v; }
    baseSh = run ? atomicAdd(&cntGt[b * 64], run) : 0u;
  }
  __syncthreads();
  unsigned pos = baseSh + sc[tid];
  for (int n = start + tid; n < end; n += 256) {
    unsigned kv = kb[n];
    if (kv > K) {
      sel[(size_t)b * TOPK + pos++] = (unsigned)n;
    } else if (kv == K) {
      unsigned p = atomicAdd(&cntEq[b * 64], 1u);
      if (p < EQCAP) eq[(size_t)b * EQCAP + p] = (unsigned)n;
    }
  }
}

// ---------------- K8: rank boundary ties by index (cnt is tiny) ----------------
__global__ __launch_bounds__(256) void k_resolve2(const unsigned* __restrict__ eq,
                                                  const unsigned* __restrict__ cntEq,
                                                  const unsigned* __restrict__ meta,
                                                  unsigned* __restrict__ sel) {
  __shared__ unsigned lst[EQCAP];
  int b = blockIdx.x, t = threadIdx.x;
  unsigned cnt = cntEq[b * 64];
  if (cnt > EQCAP) cnt = EQCAP;
  unsigned nG = meta[b * 8 + 5], nE = meta[b * 8 + 6];
  for (unsigned j = t; j < cnt; j += 256) lst[j] = eq[(size_t)b * EQCAP + j];
  __syncthreads();
  for (unsigned j = t; j < cnt; j += 256) {
    unsigned my = lst[j];
    unsigned rank = 0;
    for (unsigned k = 0; k < cnt; ++k) rank += (lst[k] < my);
    if (rank < nE) sel[(size_t)b * TOPK + nG + rank] = my;
  }
}

// ---------------- K9: bitonic sort 6000 candidates by (score desc, idx asc) ----------------
__global__ __launch_bounds__(1024) void k_sort(const float4* __restrict__ anchors,
                                               const int* __restrict__ isz,
                                               const unsigned* __restrict__ keys,
                                               const float4* __restrict__ deltas,
                                               const unsigned* __restrict__ sel,
                                               unsigned* __restrict__ sIdx,
                                               unsigned* __restrict__ sKey,
                                               float4* __restrict__ sBox,
                                               float* __restrict__ sAr) {
  __shared__ u64 skey[8192];  // 64 KB
  int b = blockIdx.x, tid = threadIdx.x;
  for (int p = tid; p < 8192; p += 1024) {
    u64 kk = 0;
    if (p < TOPK) {
      unsigned n = sel[(size_t)b * TOPK + p];
      kk = ((u64)keys[(size_t)b * NN + n] << 32) | (unsigned)(NN - 1 - (int)n);
    }
    skey[p] = kk;
  }
  __syncthreads();
  for (unsigned k = 2; k <= 8192; k <<= 1) {
    for (unsigned j = k >> 1; j > 0; j >>= 1) {
      for (unsigned p = tid; p < 4096; p += 1024) {
        unsigned i = ((p & ~(j - 1)) << 1) | (p & (j - 1));
        unsigned x = i | j;
        u64 a = skey[i], c = skey[x];
        bool desc = ((i & k) == 0);
        if (desc ? (a < c) : (a > c)) { skey[i] = c; skey[x] = a; }
      }
      __syncthreads();
    }
  }
  float H1 = (float)isz[2 * b] - 1.0f;
  float W1 = (float)isz[2 * b + 1] - 1.0f;
  for (int i = tid; i < TOPK; i += 1024) {
    u64 kk = skey[i];
    unsigned n = (unsigned)(NN - 1) - (unsigned)(kk & 0xFFFFFFFFull);
    sIdx[(size_t)b * TOPK + i] = n;
    sKey[(size_t)b * TOPK + i] = (unsigned)(kk >> 32);
    float4 a = anchors[(size_t)b * NN + n];
    float4 d = deltas[(size_t)b * NN + n];
    float x1, y1, x2, y2; bool valid;
    decode_box(a, d, W1, H1, x1, y1, x2, y2, valid);
    sBox[(size_t)b * TOPK + i] = make_float4(x1, y1, x2, y2);
    sAr[(size_t)b * TOPK + i] = (x2 - x1) * (y2 - y1);
  }
}

// ---------------- K10: triangular IoU>0.7 bit matrix (balanced tiles, no div) ----------------
// pred = RN32(inter/uni) > 0.7f  <=>  uni>0 && (double)inter >= T*(double)uni,
// T = midpoint(0.7f, succ(0.7f)) (0.7f mantissa odd -> tie rounds up -> ">=").
// T has 25 sig bits, uni 24 -> T*uni exact in f64: decision is bit-identical.
__global__ __launch_bounds__(256) void k_iou(const float4* __restrict__ sBox,
                                             const float* __restrict__ sAr,
                                             u64* __restrict__ mat) {
  int Bk = blockIdx.x;      // row block: rows [64*Bk, 64*Bk+64)
  int c = blockIdx.y;       // column chunk: words [16c, 16c+16)
  int b = blockIdx.z;
  int wlo = c * 16;
  int whi = wlo + 16 > 94 ? 94 : wlo + 16;
  if (wlo < Bk) wlo = Bk;
  if (wlo >= whi) return;   // tile fully below diagonal
  int tid = threadIdx.x, wv = tid >> 6, lane = tid & 63;
  __shared__ float4 cb[1024];
  __shared__ float ca[1024];
  __shared__ float4 rb[64];
  __shared__ float ra[64];
  const float4* sb = sBox + (size_t)b * TOPK;
  const float* sa = sAr + (size_t)b * TOPK;
  for (int u = tid; u < 1024; u += 256) {
    int j = c * 1024 + u;
    int jc = j < TOPK ? j : TOPK - 1;
    cb[u] = sb[jc];
    ca[u] = sa[jc];
  }
  if (tid < 64) {
    int i = Bk * 64 + tid;
    int ic = i < TOPK ? i : TOPK - 1;
    rb[tid] = sb[ic];
    ra[tid] = sa[ic];
  }
  __syncthreads();
  const double T = (double)0.7f + 0x1p-25;
  size_t matb = (size_t)b * MW;
  for (int g = 0; g < 4; ++g) {
    int r0 = wv * 16 + g * 4;
    float4 r4[4]; float rar[4]; size_t ro[4]; bool rok[4];
    for (int k = 0; k < 4; ++k) {
      int i = Bk * 64 + r0 + k;
      r4[k] = rb[r0 + k];
      rar[k] = ra[r0 + k];
      rok[k] = i < TOPK;
      int rm = i & 63;
      ro[k] = matb + (size_t)(94 * i - (32 * Bk * (Bk - 1) + Bk * rm)) - (size_t)Bk;
    }
    for (int w = wlo; w < whi; ++w) {
      int u = (w - c * 16) * 64 + lane;
      float4 c4 = cb[u];
      float car = ca[u];
#pragma unroll
      for (int k = 0; k < 4; ++k) {
        if (!rok[k]) continue;  // wave-uniform
        float iw = fminf(c4.z, r4[k].z) - fmaxf(c4.x, r4[k].x);
        iw = fmaxf(iw, 0.0f);
        float ih = fminf(c4.w, r4[k].w) - fmaxf(c4.y, r4[k].y);
        ih = fmaxf(ih, 0.0f);
        float inter = iw * ih;
        float uni = (car + rar[k]) - inter;
        bool pred = (uni > 0.0f) && ((double)inter >= T * (double)uni);
        u64 w64 = __ballot(pred);
        if (lane == 0) mat[ro[k] + (size_t)w] = w64;
      }
    }
  }
}

// ---------------- K11: pick-driven scan ----------------
__global__ __launch_bounds__(1024) void k_scan(const float4* __restrict__ anchors,
                                               const int* __restrict__ isz,
                                               const float* __restrict__ logits,
                                               const float4* __restrict__ deltas,
                                               const unsigned* __restrict__ sIdx,
                                               const unsigned* __restrict__ sKey,
                                               const u64* __restrict__ mat,
                                               float* __restrict__ out) {
  __shared__ u64 rmW[94];
  __shared__ u64 diagb[2][64];
  __shared__ unsigned keyb[2][64];
  __shared__ unsigned idxb[2][64];
  __shared__ unsigned keepL[POSTK];
  __shared__ unsigned picksList[64];
  __shared__ int nkSh, npicksSh, allInvSh;
  int b = blockIdx.x, tid = threadIdx.x, lane = tid & 63, wv = tid >> 6;
  const u64* mb = mat + (size_t)b * MW;
  const size_t bT = (size_t)b * TOPK;
  if (tid < 94) rmW[tid] = 0;
  if (tid == 0) { nkSh = 0; allInvSh = 0; }
  if (wv == 1) {  // prefetch batch 0 (rows 0..63: diag word is rowOff(i)+0 = 94*i)
    diagb[0][lane] = mb[(size_t)(94 * lane)];
    keyb[0][lane] = sKey[bT + lane];
    idxb[0][lane] = sIdx[bT + lane];
  }
  __syncthreads();
  for (int B = 0; B < 94; ++B) {
    if (nkSh >= POSTK || allInvSh) break;  // uniform (LDS) -> no divergence
    int par = B & 1;
    if (wv == 0) {
      unsigned skl = keyb[par][lane];
      unsigned nl = idxb[par][lane];
      u64 w0 = diagb[par][lane];
      u64 v64 = __ballot(skl > KEY_NEGHALF);
      int base = nkSh;
      u64 alive = v64 & ~rmW[B];
      u64 picks = 0;
      int cnt = 0, lim = POSTK - base;
      while (alive && cnt < lim) {
        int c = __ffsll(alive) - 1;
        picks |= 1ull << c;
        ++cnt;
        u64 sup = __shfl(w0, c);   // row c's within-batch suppression word
        alive &= ~sup;
        alive &= ~((2ull << c) - 1ull);  // clear bits <= c (c=63 wraps to all-ones)
      }
      int rank = __popcll(picks & ((1ull << lane) - 1ull));
      if ((picks >> lane) & 1ull) {
        keepL[base + rank] = nl;       // pick order == ascending lane == argmax order
        picksList[rank] = (unsigned)lane;
      }
      if (lane == 0) { npicksSh = cnt; nkSh = base + cnt; allInvSh = (v64 == 0); }
    } else if (wv == 1) {
      int nb = B + 1;
      if (nb < 94) {
        int i2 = nb * 64 + lane;
        if (i2 < TOPK) {
          int off2 = 94 * i2 - 32 * nb * (nb - 1) - nb * lane;  // rowOff(i2), word nb is first
          diagb[nb & 1][lane] = mb[(size_t)off2];
          keyb[nb & 1][lane] = sKey[bT + i2];
          idxb[nb & 1][lane] = sIdx[bT + i2];
        } else {
          diagb[nb & 1][lane] = 0;
          keyb[nb & 1][lane] = 0;
          idxb[nb & 1][lane] = 0;
        }
      }
    }
    __syncthreads();  // picks/npicks published; prefetch landed
    int np = npicksSh;
    if (tid >= 128 && np > 0) {
      int t = tid - 128;
      int w = B + 1 + (t >> 3);  // word index; 8 threads per word
      int k = t & 7;
      if (w < 94) {
        int base94 = 6016 * B - 32 * B * (B - 1);  // rowOff(B*64)
        int span = 94 - B;                          // row length; rowOff(B*64+c)=base94+span*c
        u64 a0 = 0, a1 = 0;
        int j = k;
        for (; j + 8 < np; j += 16) {  // two independent load chains
          a0 |= mb[(size_t)(base94 + span * (int)picksList[j] + (w - B))];
          a1 |= mb[(size_t)(base94 + span * (int)picksList[j + 8] + (w - B))];
        }
        if (j < np) a0 |= mb[(size_t)(base94 + span * (int)picksList[j] + (w - B))];
        a0 |= a1;
        if (a0) atomicOr(&rmW[w], a0);
      }
    }
    __syncthreads();  // rmW final for batch B+1
  }
  int nkF = nkSh;
  float H1 = (float)isz[2 * b] - 1.0f;
  float W1 = (float)isz[2 * b + 1] - 1.0f;
  const size_t base = (size_t)b * NN;
  for (int q = tid; q < POSTK; q += 1024) {
    float px1 = 0.f, py1 = 0.f, px2 = 0.f, py2 = 0.f;
    float L = 1e-8f, d0 = 0.f, d1 = 0.f, d2 = 0.f, d3 = 0.f, V = 0.f;
    if (q < nkF) {
      unsigned n = keepL[q];
      float4 a = anchors[base + n];
      float4 d = deltas[base + n];
      float x1, y1, x2, y2; bool valid;
      decode_box(a, d, W1, H1, x1, y1, x2, y2, valid);
      px1 = x1; py1 = y1; px2 = x2; py2 = y2;
      L = logits[base + n];
      d0 = d.x; d1 = d.y; d2 = d.z; d3 = d.w;
      V = 1.0f;
    }
    size_t row = (size_t)b * POSTK + q;
    float* outP = out + row * 4;
    outP[0] = px1; outP[1] = py1; outP[2] = px2; outP[3] = py2;
    out[(size_t)BN * POSTK * 4 + row] = L;
    float* outD = out + (size_t)BN * POSTK * 5 + row * 4;
    outD[0] = d0; outD[1] = d1; outD[2] = d2; outD[3] = d3;
    out[(size_t)BN * POSTK * 9 + row] = V;
  }
}

extern "C" void kernel_launch(void* const* d_in, const int* in_sizes, int n_in,
                              void* d_out, int out_size, void* d_ws, size_t ws_size,
                              hipStream_t stream) {
  const float4* anchors = (const float4*)d_in[0];
  const int* isz = (const int*)d_in[1];
  const float* logits = (const float*)d_in[2];
  const float4* deltas = (const float4*)d_in[3];
  float* out = (float*)d_out;

  // Workspace layout (u32 units). The bit matrix (36.6 MB) aliases the
  // histogram/keys/eq region — all of it is dead before k_iou writes.
  unsigned* W = (unsigned*)d_ws;
  unsigned* hist1 = W;                       // 16*65536
  unsigned* keys = W + 1048576;              // 16*200000
  unsigned* hist0 = W + 4248576;             // 16*8*256 (8 shards/image)
  unsigned* hist2 = W + 4281344;             // 16*256
  unsigned* cntGt = W + 4285440;             // 16*64 (one cache line per image)
  unsigned* meta = W + 4286464;              // 16*8
  unsigned* cntEq = W + 4286592;             // 16*64 (one cache line per image)
  unsigned* eq = W + 4287616;                // 16*EQCAP (boundary-tie indices)
  u64* mat = (u64*)d_ws;                     // 16*MW u64 = 36.58 MB (aliases above)
  unsigned* T = W + 9143808;                 // tail (non-aliased)
  unsigned* sel = T;                         // 16*6000
  unsigned* sIdx = T + 96000;                // 16*6000
  unsigned* sKey = T + 192000;               // 16*6000
  float4* sBox = (float4*)(T + 288000);      // 16*6000 float4
  float* sAr = (float*)(T + 672000);         // 16*6000  (total ws ~39.7 MB)

  hipMemsetAsync(hist1, 0, (size_t)1048576 * 4, stream);
  hipMemsetAsync(hist0, 0, (size_t)(32768 + 4096 + 1024 + 128 + 1024) * 4, stream);

  dim3 gN((NN + 255) / 256, BN);
  k_score<<<gN, 256, 0, stream>>>(anchors, isz, logits, deltas, keys, hist0);
  k_sel0<<<BN, 256, 0, stream>>>(hist0, meta);
  k_h1<<<gN, 256, 0, stream>>>(keys, meta, hist1);
  k_sel1<<<BN, 256, 0, stream>>>(hist1, meta);
  k_h2<<<gN, 256, 0, stream>>>(keys, meta, hist2);
  k_sel2<<<BN, 256, 0, stream>>>(hist2, meta);
  k_compact<<<dim3(25, BN), 256, 0, stream>>>(keys, meta, cntGt, sel, cntEq, eq);
  k_resolve2<<<BN, 256, 0, stream>>>(eq, cntEq, meta, sel);
  k_sort<<<BN, 1024, 0, stream>>>(anchors, isz, keys, deltas, sel, sIdx, sKey, sBox, sAr);
  k_iou<<<dim3(94, 6, BN), 256, 0, stream>>>(sBox, sAr, mat);
  k_scan<<<BN, 1024, 0, stream>>>(anchors, isz, logits, deltas, sIdx, sKey, mat, out);
}

// Round 7
// 627.738 us; speedup vs baseline: 8.6142x; 1.0246x over previous
//
#include <hip/hip_runtime.h>

#define BN 16
#define NN 200000
#define TOPK 6000
#define POSTK 1000
#define KEY_NEGHALF 0x40FFFFFFu /* key_of(-0.5f); valid <=> key > this */
#define EQCAP 8192              /* max boundary ties tracked per image */

// Decision-critical math must match CPU reference bit-for-bit: no FMA contraction.
#pragma clang fp contract(off)

typedef unsigned long long u64;

__device__ __forceinline__ float exp_cr(float x) {
  return (float)exp((double)x);  // correctly-rounded f32 exp via double
}

__device__ __forceinline__ unsigned key_of(float s) {
  unsigned u = __float_as_uint(s);
  return (u & 0x80000000u) ? ~u : (u | 0x80000000u);
}

__device__ __forceinline__ void decode_box(float4 a, float4 d, float W1, float H1,
                                           float& x1, float& y1, float& x2, float& y2,
                                           bool& valid) {
  float aw = a.z - a.x;
  float ah = a.w - a.y;
  float ax = a.x + 0.5f * aw;
  float ay = a.y + 0.5f * ah;
  float px = ax + d.x * aw;
  float py = ay + d.y * ah;
  float cz = fminf(fmaxf(d.z, -10.0f), 10.0f);
  float cw = fminf(fmaxf(d.w, -10.0f), 10.0f);
  float pw = aw * exp_cr(cz);
  float ph = ah * exp_cr(cw);
  x1 = fminf(fmaxf(px - 0.5f * pw, 0.0f), W1);
  y1 = fminf(fmaxf(py - 0.5f * ph, 0.0f), H1);
  x2 = fminf(fmaxf(px + 0.5f * pw, 0.0f), W1);
  y2 = fminf(fmaxf(py + 0.5f * ph, 0.0f), H1);
  valid = ((x2 - x1) >= 16.0f) && ((y2 - y1) >= 16.0f);
}

__device__ __forceinline__ float score_of(float lg, bool valid) {
  float e = exp_cr(-lg);
  float s = 1.0f / (1.0f + e);
  return valid ? s : -1.0f;
}

// ---------------- K1: keys + wave-aggregated LDS histogram + sharded merge ----------------
__global__ __launch_bounds__(256) void k_score(const float4* __restrict__ anchors,
                                               const int* __restrict__ isz,
                                               const float* __restrict__ logits,
                                               const float4* __restrict__ deltas,
                                               unsigned* __restrict__ keys,
                                               unsigned* __restrict__ hist0) {
  __shared__ unsigned h[256];
  int b = blockIdx.y;
  int idx = blockIdx.x * 256 + threadIdx.x;
  int lane = threadIdx.x & 63;
  h[threadIdx.x] = 0;
  __syncthreads();
  unsigned bin = 0;
  bool active = idx < NN;
  if (active) {
    size_t i = (size_t)b * NN + idx;
    float4 a = anchors[i];
    float4 d = deltas[i];
    float H1 = (float)isz[2 * b] - 1.0f;
    float W1 = (float)isz[2 * b + 1] - 1.0f;
    float x1, y1, x2, y2; bool valid;
    decode_box(a, d, W1, H1, x1, y1, x2, y2, valid);
    float sc = score_of(logits[i], valid);
    unsigned key = key_of(sc);
    keys[i] = key;
    bin = key >> 24;
  }
  // match-any aggregation: one LDS atomic per distinct bin per wave (~3 typical)
  u64 act = __ballot(active);
  while (act) {
    int l = __ffsll(act) - 1;
    unsigned vb = __shfl(bin, l);
    u64 same = __ballot(bin == vb) & act;
    if (lane == l) atomicAdd(&h[vb], (unsigned)__popcll(same));
    act &= ~same;
  }
  __syncthreads();
  unsigned c = h[threadIdx.x];
  if (c) atomicAdd(&hist0[((size_t)b * 8 + (blockIdx.x & 7)) * 256 + threadIdx.x], c);
}

// ---------------- K2: top byte bin (sum 8 shards) ----------------
__global__ void k_sel0(const unsigned* __restrict__ hist0, unsigned* __restrict__ meta) {
  int b = blockIdx.x, t = threadIdx.x;
  __shared__ unsigned c[256];
  unsigned s = 0;
  for (int sh = 0; sh < 8; ++sh) s += hist0[((size_t)b * 8 + sh) * 256 + t];
  c[t] = s;
  __syncthreads();
  if (t == 0) {
    unsigned cum = 0;
    for (int u = 255; u >= 0; --u) {
      if (cum + c[u] >= TOPK) { meta[b * 8 + 0] = (unsigned)u; meta[b * 8 + 1] = cum; break; }
      cum += c[u];
    }
  }
}

// ---------------- K3: mid-16-bit histogram within byte bin ----------------
__global__ __launch_bounds__(256) void k_h1(const unsigned* __restrict__ keys,
                                            const unsigned* __restrict__ meta,
                                            unsigned* __restrict__ hist1) {
  int b = blockIdx.y;
  int idx = blockIdx.x * 256 + threadIdx.x;
  if (idx >= NN) return;
  unsigned key = keys[(size_t)b * NN + idx];
  unsigned B0 = meta[b * 8 + 0];
  if ((key >> 24) == B0)
    atomicAdd(&hist1[(size_t)b * 65536 + ((key >> 8) & 0xFFFFu)], 1u);
}

// ---------------- K4: find mid-16-bit value ----------------
__global__ void k_sel1(const unsigned* __restrict__ hist1, unsigned* __restrict__ meta) {
  int b = blockIdx.x, t = threadIdx.x;
  __shared__ unsigned part[256];
  __shared__ unsigned above[256];
  const unsigned* h = hist1 + (size_t)b * 65536;
  unsigned cA0 = meta[b * 8 + 1];
  unsigned R1 = TOPK - cA0;
  int base = t * 256;
  unsigned sum = 0;
  for (int j = 0; j < 256; ++j) sum += h[base + j];
  part[t] = sum;
  __syncthreads();
  if (t == 0) {
    unsigned run = 0;
    for (int u = 255; u >= 0; --u) { above[u] = run; run += part[u]; }
  }
  __syncthreads();
  unsigned ab = above[t];
  if (ab < R1 && ab + part[t] >= R1) {
    unsigned cum = ab;
    for (int j = 255; j >= 0; --j) {
      unsigned c = h[base + j];
      if (cum + c >= R1) {
        meta[b * 8 + 2] = (unsigned)(base + j);
        meta[b * 8 + 3] = cA0 + cum;
        break;
      }
      cum += c;
    }
  }
}

// ---------------- K5: low-byte histogram within 24-bit prefix ----------------
__global__ __launch_bounds__(256) void k_h2(const unsigned* __restrict__ keys,
                                            const unsigned* __restrict__ meta,
                                            unsigned* __restrict__ hist2) {
  int b = blockIdx.y;
  int idx = blockIdx.x * 256 + threadIdx.x;
  if (idx >= NN) return;
  unsigned key = keys[(size_t)b * NN + idx];
  unsigned pref = (meta[b * 8 + 0] << 16) | meta[b * 8 + 2];
  if ((key >> 8) == pref)
    atomicAdd(&hist2[b * 256 + (key & 0xFFu)], 1u);
}

// ---------------- K6: exact threshold key ----------------
__global__ void k_sel2(const unsigned* __restrict__ hist2, unsigned* __restrict__ meta) {
  int b = blockIdx.x, t = threadIdx.x;
  __shared__ unsigned c[256];
  c[t] = hist2[b * 256 + t];
  __syncthreads();
  if (t == 0) {
    unsigned R2 = TOPK - meta[b * 8 + 3];
    unsigned cum = 0;
    for (int u = 255; u >= 0; --u) {
      if (cum + c[u] >= R2) {
        unsigned K = (meta[b * 8 + 0] << 24) | (meta[b * 8 + 2] << 8) | (unsigned)u;
        unsigned nG = meta[b * 8 + 3] + cum;
        meta[b * 8 + 4] = K;
        meta[b * 8 + 5] = nG;
        meta[b * 8 + 6] = TOPK - nG;
        break;
      }
      cum += c[u];
    }
  }
}

// ---------------- K7: compact strictly-greater + collect boundary ties ----------------
__global__ __launch_bounds__(256) void k_compact(const unsigned* __restrict__ keys,
                                                 const unsigned* __restrict__ meta,
                                                 unsigned* __restrict__ cntGt,
                                                 unsigned* __restrict__ sel,
                                                 unsigned* __restrict__ cntEq,
                                                 unsigned* __restrict__ eq) {
  __shared__ unsigned sc[256];
  __shared__ unsigned baseSh;
  int b = blockIdx.y, tid = threadIdx.x;
  const unsigned* kb = keys + (size_t)b * NN;
  unsigned K = meta[b * 8 + 4];
  int start = blockIdx.x * 8000;
  int end = start + 8000 < NN ? start + 8000 : NN;
  unsigned cnt = 0;
  for (int n = start + tid; n < end; n += 256) cnt += (kb[n] > K);
  sc[tid] = cnt;
  __syncthreads();
  if (tid == 0) {
    unsigned run = 0;
    for (int u = 0; u < 256; ++u) { unsigned v = sc[u]; sc[u] = run; run += v; }
    baseSh = run ? atomicAdd(&cntGt[b * 64], run) : 0u;
  }
  __syncthreads();
  unsigned pos = baseSh + sc[tid];
  for (int n = start + tid; n < end; n += 256) {
    unsigned kv = kb[n];
    if (kv > K) {
      sel[(size_t)b * TOPK + pos++] = (unsigned)n;
    } else if (kv == K) {
      unsigned p = atomicAdd(&cntEq[b * 64], 1u);
      if (p < EQCAP) eq[(size_t)b * EQCAP + p] = (unsigned)n;
    }
  }
}

// ---------------- K8: rank boundary ties by index (cnt is tiny) ----------------
__global__ __launch_bounds__(256) void k_resolve2(const unsigned* __restrict__ eq,
                                                  const unsigned* __restrict__ cntEq,
                                                  const unsigned* __restrict__ meta,
                                                  unsigned* __restrict__ sel) {
  __shared__ unsigned lst[EQCAP];
  int b = blockIdx.x, t = threadIdx.x;
  unsigned cnt = cntEq[b * 64];
  if (cnt > EQCAP) cnt = EQCAP;
  unsigned nG = meta[b * 8 + 5], nE = meta[b * 8 + 6];
  for (unsigned j = t; j < cnt; j += 256) lst[j] = eq[(size_t)b * EQCAP + j];
  __syncthreads();
  for (unsigned j = t; j < cnt; j += 256) {
    unsigned my = lst[j];
    unsigned rank = 0;
    for (unsigned k = 0; k < cnt; ++k) rank += (lst[k] < my);
    if (rank < nE) sel[(size_t)b * TOPK + nG + rank] = my;
  }
}

// ---------------- K9: bitonic sort 6000 candidates by (score desc, idx asc) ----------------
__global__ __launch_bounds__(1024) void k_sort(const float4* __restrict__ anchors,
                                               const int* __restrict__ isz,
                                               const unsigned* __restrict__ keys,
                                               const float4* __restrict__ deltas,
                                               const unsigned* __restrict__ sel,
                                               unsigned* __restrict__ sIdx,
                                               unsigned* __restrict__ sKey,
                                               float4* __restrict__ sBox,
                                               float* __restrict__ sAr) {
  __shared__ u64 skey[8192];  // 64 KB
  int b = blockIdx.x, tid = threadIdx.x;
  for (int p = tid; p < 8192; p += 1024) {
    u64 kk = 0;
    if (p < TOPK) {
      unsigned n = sel[(size_t)b * TOPK + p];
      kk = ((u64)keys[(size_t)b * NN + n] << 32) | (unsigned)(NN - 1 - (int)n);
    }
    skey[p] = kk;
  }
  __syncthreads();
  for (unsigned k = 2; k <= 8192; k <<= 1) {
    for (unsigned j = k >> 1; j > 0; j >>= 1) {
      for (unsigned p = tid; p < 4096; p += 1024) {
        unsigned i = ((p & ~(j - 1)) << 1) | (p & (j - 1));
        unsigned x = i | j;
        u64 a = skey[i], c = skey[x];
        bool desc = ((i & k) == 0);
        if (desc ? (a < c) : (a > c)) { skey[i] = c; skey[x] = a; }
      }
      __syncthreads();
    }
  }
  float H1 = (float)isz[2 * b] - 1.0f;
  float W1 = (float)isz[2 * b + 1] - 1.0f;
  for (int i = tid; i < TOPK; i += 1024) {
    u64 kk = skey[i];
    unsigned n = (unsigned)(NN - 1) - (unsigned)(kk & 0xFFFFFFFFull);
    sIdx[(size_t)b * TOPK + i] = n;
    sKey[(size_t)b * TOPK + i] = (unsigned)(kk >> 32);
    float4 a = anchors[(size_t)b * NN + n];
    float4 d = deltas[(size_t)b * NN + n];
    float x1, y1, x2, y2; bool valid;
    decode_box(a, d, W1, H1, x1, y1, x2, y2, valid);
    sBox[(size_t)b * TOPK + i] = make_float4(x1, y1, x2, y2);
    sAr[(size_t)b * TOPK + i] = (x2 - x1) * (y2 - y1);
  }
}

// ---------------- K10: fused sequential NMS (replaces bit-matrix + scan) ----------------
// Only ~3M IoUs are decision-relevant (candidate vs already-kept + diagonal
// blocks) vs 292M in the full matrix. Per 64-candidate batch:
//   1. every wave tests the batch (lane = candidate, regs) vs the kept list
//      (LDS broadcast, strided by wave) -> ballot -> OR into suppSh;
//   2. wave v computes 4 diagonal-block rows via __shfl broadcast + ballot;
//   3. wave0 pick loop: ffs + one 64-bit shuffle per pick (register diag),
//      picked lanes append their box to the kept list in LDS.
// IoU math bit-identical: same f32 sequence, f64 threshold compare
// (T = midpoint(0.7f, succ(0.7f)); T*uni exact in f64).
__global__ __launch_bounds__(1024) void k_nms(const float4* __restrict__ sBox,
                                              const float* __restrict__ sAr,
                                              const unsigned* __restrict__ sIdx,
                                              const unsigned* __restrict__ sKey,
                                              const float4* __restrict__ anchors,
                                              const int* __restrict__ isz,
                                              const float* __restrict__ logits,
                                              const float4* __restrict__ deltas,
                                              float* __restrict__ out) {
  __shared__ float kx1[POSTK], ky1[POSTK], kx2[POSTK], ky2[POSTK], kar[POSTK];  // 20KB
  __shared__ unsigned keptPos[POSTK];  // sorted positions of keeps
  __shared__ u64 diagb[64];
  __shared__ u64 suppSh;
  __shared__ int nkSh, stopSh;
  int b = blockIdx.x, tid = threadIdx.x, lane = tid & 63, wv = tid >> 6;
  const size_t bT = (size_t)b * TOPK;
  if (tid == 0) { nkSh = 0; stopSh = 0; }
  __syncthreads();
  const double T = (double)0.7f + 0x1p-25;
  for (int B = 0; B < 94; ++B) {
    // all waves load the same 64 batch candidates (lane = candidate)
    int pos = B * 64 + lane;
    float cx1 = 0.f, cy1 = 0.f, cx2 = 0.f, cy2 = 0.f, car = 0.f;
    unsigned ckey = 0;
    if (pos < TOPK) {
      float4 bb = sBox[bT + pos];
      cx1 = bb.x; cy1 = bb.y; cx2 = bb.z; cy2 = bb.w;
      car = sAr[bT + pos];
      ckey = sKey[bT + pos];
    }
    int nk0 = nkSh;
    if (tid == 0) suppSh = 0;
    __syncthreads();
    // 1. suppression vs kept list (broadcast reads; iters independent -> ILP)
    bool sup = false;
    for (int k = wv; k < nk0; k += 16) {
      float rx1 = kx1[k], ry1 = ky1[k], rx2 = kx2[k], ry2 = ky2[k], rar = kar[k];
      float iw = fminf(cx2, rx2) - fmaxf(cx1, rx1);
      iw = fmaxf(iw, 0.0f);
      float ih = fminf(cy2, ry2) - fmaxf(cy1, ry1);
      ih = fmaxf(ih, 0.0f);
      float inter = iw * ih;
      float uni = (car + rar) - inter;
      sup = sup || ((uni > 0.0f) && ((double)inter >= T * (double)uni));
    }
    u64 wsup = __ballot(sup);
    if (wsup && lane == 0) atomicOr(&suppSh, wsup);
    // 2. diagonal block rows for this wave (rows 4wv..4wv+3)
    for (int rr = 0; rr < 4; ++rr) {
      int r = wv * 4 + rr;
      float rx1 = __shfl(cx1, r), ry1 = __shfl(cy1, r);
      float rx2 = __shfl(cx2, r), ry2 = __shfl(cy2, r);
      float rar = __shfl(car, r);
      float iw = fminf(cx2, rx2) - fmaxf(cx1, rx1);
      iw = fmaxf(iw, 0.0f);
      float ih = fminf(cy2, ry2) - fmaxf(cy1, ry1);
      ih = fmaxf(ih, 0.0f);
      float inter = iw * ih;
      float uni = (car + rar) - inter;
      bool pd = (uni > 0.0f) && ((double)inter >= T * (double)uni);
      u64 dw = __ballot(pd);
      if (lane == 0) diagb[r] = dw;
    }
    __syncthreads();
    // 3. wave0 pick loop
    if (wv == 0) {
      u64 w0 = diagb[lane];
      u64 v64 = __ballot(ckey > KEY_NEGHALF);
      u64 alive = v64 & ~suppSh;
      u64 picks = 0;
      int cnt = 0, lim = POSTK - nk0;
      while (alive && cnt < lim) {
        int c = __ffsll(alive) - 1;
        picks |= 1ull << c;
        ++cnt;
        u64 s2 = __shfl(w0, c);          // row c's within-batch suppression
        alive &= ~s2;
        alive &= ~((2ull << c) - 1ull);  // clear bits <= c
      }
      int rank = __popcll(picks & ((1ull << lane) - 1ull));
      if ((picks >> lane) & 1ull) {      // append picked boxes (pick order = lane order)
        int slot = nk0 + rank;
        kx1[slot] = cx1; ky1[slot] = cy1; kx2[slot] = cx2; ky2[slot] = cy2;
        kar[slot] = car;
        keptPos[slot] = (unsigned)pos;
      }
      if (lane == 0) { nkSh = nk0 + cnt; stopSh = (v64 == 0); }
    }
    __syncthreads();  // picks/kept visible; nkSh/stopSh uniform
    if (nkSh >= POSTK || stopSh) break;
  }
  int nkF = nkSh;
  float H1 = (float)isz[2 * b] - 1.0f;
  float W1 = (float)isz[2 * b + 1] - 1.0f;
  const size_t base = (size_t)b * NN;
  for (int q = tid; q < POSTK; q += 1024) {
    float px1 = 0.f, py1 = 0.f, px2 = 0.f, py2 = 0.f;
    float L = 1e-8f, d0 = 0.f, d1 = 0.f, d2 = 0.f, d3 = 0.f, V = 0.f;
    if (q < nkF) {
      unsigned n = sIdx[bT + keptPos[q]];
      float4 a = anchors[base + n];
      float4 d = deltas[base + n];
      float x1, y1, x2, y2; bool valid;
      decode_box(a, d, W1, H1, x1, y1, x2, y2, valid);
      px1 = x1; py1 = y1; px2 = x2; py2 = y2;
      L = logits[base + n];
      d0 = d.x; d1 = d.y; d2 = d.z; d3 = d.w;
      V = 1.0f;
    }
    size_t row = (size_t)b * POSTK + q;
    float* outP = out + row * 4;
    outP[0] = px1; outP[1] = py1; outP[2] = px2; outP[3] = py2;
    out[(size_t)BN * POSTK * 4 + row] = L;
    float* outD = out + (size_t)BN * POSTK * 5 + row * 4;
    outD[0] = d0; outD[1] = d1; outD[2] = d2; outD[3] = d3;
    out[(size_t)BN * POSTK * 9 + row] = V;
  }
}

extern "C" void kernel_launch(void* const* d_in, const int* in_sizes, int n_in,
                              void* d_out, int out_size, void* d_ws, size_t ws_size,
                              hipStream_t stream) {
  const float4* anchors = (const float4*)d_in[0];
  const int* isz = (const int*)d_in[1];
  const float* logits = (const float*)d_in[2];
  const float4* deltas = (const float4*)d_in[3];
  float* out = (float*)d_out;

  // Workspace layout (u32 units). No bit matrix anymore.
  unsigned* W = (unsigned*)d_ws;
  unsigned* hist1 = W;                       // 16*65536
  unsigned* keys = W + 1048576;              // 16*200000
  unsigned* hist0 = W + 4248576;             // 16*8*256 (8 shards/image)
  unsigned* hist2 = W + 4281344;             // 16*256
  unsigned* cntGt = W + 4285440;             // 16*64 (one cache line per image)
  unsigned* meta = W + 4286464;              // 16*8
  unsigned* cntEq = W + 4286592;             // 16*64 (one cache line per image)
  unsigned* eq = W + 4287616;                // 16*EQCAP (boundary-tie indices)
  unsigned* T = W + 9143808;                 // tail
  unsigned* sel = T;                         // 16*6000
  unsigned* sIdx = T + 96000;                // 16*6000
  unsigned* sKey = T + 192000;               // 16*6000
  float4* sBox = (float4*)(T + 288000);      // 16*6000 float4
  float* sAr = (float*)(T + 672000);         // 16*6000

  hipMemsetAsync(hist1, 0, (size_t)1048576 * 4, stream);
  hipMemsetAsync(hist0, 0, (size_t)(32768 + 4096 + 1024 + 128 + 1024) * 4, stream);

  dim3 gN((NN + 255) / 256, BN);
  k_score<<<gN, 256, 0, stream>>>(anchors, isz, logits, deltas, keys, hist0);
  k_sel0<<<BN, 256, 0, stream>>>(hist0, meta);
  k_h1<<<gN, 256, 0, stream>>>(keys, meta, hist1);
  k_sel1<<<BN, 256, 0, stream>>>(hist1, meta);
  k_h2<<<gN, 256, 0, stream>>>(keys, meta, hist2);
  k_sel2<<<BN, 256, 0, stream>>>(hist2, meta);
  k_compact<<<dim3(25, BN), 256, 0, stream>>>(keys, meta, cntGt, sel, cntEq, eq);
  k_resolve2<<<BN, 256, 0, stream>>>(eq, cntEq, meta, sel);
  k_sort<<<BN, 1024, 0, stream>>>(anchors, isz, keys, deltas, sel, sIdx, sKey, sBox, sAr);
  k_nms<<<BN, 1024, 0, stream>>>(sBox, sAr, sIdx, sKey, anchors, isz, logits, deltas, out);
}